// Round 9
// baseline (903.037 us; speedup 1.0000x reference)
//
#include <hip/hip_runtime.h>
#include <hip/hip_cooperative_groups.h>

namespace cg = cooperative_groups;

typedef unsigned short ushort_t;
typedef __attribute__((ext_vector_type(8))) short short8;
typedef __attribute__((ext_vector_type(4))) float floatx4;
typedef __attribute__((ext_vector_type(4))) ushort_t us4;

#define BAR() __builtin_amdgcn_s_barrier()
#define WAITVM(n) \
  __builtin_amdgcn_s_waitcnt(0x0F70 | ((n) & 15) | (((n) >> 4) << 14))
#define RB2(a, b) __asm__ __volatile__("" : "+v"(a), "+v"(b))

template <int N>
__device__ __forceinline__ void waitvm() {
  __builtin_amdgcn_s_waitcnt(0x0F70 | (N & 15) | ((N >> 4) << 14));
}

template <int V> struct Int { static constexpr int value = V; };
template <int C, int N, typename F> struct StaticFor {
  __device__ __forceinline__ static void run(F& f) {
    f(Int<C>{});
    StaticFor<C + 1, N, F>::run(f);
  }
};
template <int N, typename F> struct StaticFor<N, N, F> {
  __device__ __forceinline__ static void run(F&) {}
};
template <int N, typename F>
__device__ __forceinline__ void static_for(F&& f) {
  StaticFor<0, N, F>::run(f);
}

// vmcnt targets: ensure chunk c's loads done; issue distance 6.
constexpr int nh(int c) { int r = 31 - c; if (r > 6) r = 6; return 2 * r; }
constexpr int nf(int c) { int r = 31 - c; if (r > 6) r = 6; return 4 * r; }

__device__ __forceinline__ ushort_t f2bf(float f) {
  union { float f; unsigned u; } v; v.f = f;
  unsigned r = v.u + 0x7fffu + ((v.u >> 16) & 1u);
  return (ushort_t)(r >> 16);
}
__device__ __forceinline__ float fast_sigmoid(float x) {
  return 1.f / (1.f + __expf(-x));
}
__device__ __forceinline__ float fast_tanh(float x) {
  return 1.f - 2.f / (__expf(2.f * x) + 1.f);
}

// register loads with compile-time byte offset
template <bool SYS, int OFF>
__device__ __forceinline__ void ldh(short8& d, const ushort_t* a) {
  if constexpr (SYS)
    __asm__ __volatile__("global_load_dwordx4 %0, %1, off offset:%2 sc0 sc1"
                         : "=v"(d) : "v"(a), "i"(OFF) : "memory");
  else
    __asm__ __volatile__("global_load_dwordx4 %0, %1, off offset:%2 sc0"
                         : "=v"(d) : "v"(a), "i"(OFF));
}
template <int OFF>
__device__ __forceinline__ void ldw(short8& d, const ushort_t* a) {
  __asm__ __volatile__("global_load_dwordx4 %0, %1, off offset:%2"
                       : "=v"(d) : "v"(a), "i"(OFF));
}

template <int AUX>
__device__ __forceinline__ void gld16x(const void* g, void* l) {
  __builtin_amdgcn_global_load_lds(
      (__attribute__((address_space(1))) void*)g,
      (__attribute__((address_space(3))) void*)l, 16, 0, AUX);
}

// ---- FF staging: 64x64 chunk, 8KB, XOR-8 swizzle ----
__device__ __forceinline__ void stage64(const ushort_t* src, int ldk,
                                        short* dst, int w, int l) {
  int r0 = (w << 3) + (l >> 3);
  int cb0 = (l & 7) ^ (r0 & 7);
  int r1 = 32 + r0;
  int cb1 = (l & 7) ^ (r1 & 7);
  gld16x<0>(src + (size_t)r0 * ldk + (cb0 << 3), dst + (w << 9));
  gld16x<0>(src + (size_t)r1 * ldk + (cb1 << 3), dst + 2048 + (w << 9));
}

__device__ __forceinline__ void compute_chunk64(const short* As, const short* Bs,
                                                floatx4 acc[2][2], int wm,
                                                int wn, int lhi, int llo) {
#pragma unroll
  for (int ks = 0; ks < 2; ++ks) {
    short8 a[2], b[2];
#pragma unroll
    for (int tm = 0; tm < 2; ++tm) {
      int m = (wm << 5) + (tm << 4) + llo;
      int ph = ((ks << 2) + lhi) ^ (m & 7);
      a[tm] = *(const short8*)(As + m * 64 + (ph << 3));
    }
#pragma unroll
    for (int tn = 0; tn < 2; ++tn) {
      int n = (wn << 5) + (tn << 4) + llo;
      int ph = ((ks << 2) + lhi) ^ (n & 7);
      b[tn] = *(const short8*)(Bs + n * 64 + (ph << 3));
    }
#pragma unroll
    for (int tm = 0; tm < 2; ++tm)
#pragma unroll
      for (int tn = 0; tn < 2; ++tn)
        acc[tm][tn] = __builtin_amdgcn_mfma_f32_16x16x32_bf16(
            a[tm], b[tn], acc[tm][tn], 0, 0, 0);
  }
}

__device__ __forceinline__ void ff_epilogue(floatx4 acc[2][2], const float* bias,
                                            ushort_t* outb, float* outf, int act,
                                            int m0, int n0, int wm, int wn,
                                            int lhi, int llo) {
#pragma unroll
  for (int tm = 0; tm < 2; ++tm)
#pragma unroll
    for (int tn = 0; tn < 2; ++tn)
#pragma unroll
      for (int i = 0; i < 4; ++i) {
        int gm = m0 + (wm << 5) + (tm << 4) + (lhi << 2) + i;
        int gn = n0 + (wn << 5) + (tn << 4) + llo;
        float v = acc[tm][tn][i];
        if (bias) v += bias[gn];
        if (act == 0) v = fmaxf(v, 0.f);
        if (outb) outb[((size_t)gm << 10) + gn] = f2bf(v);
        if (outf) outf[((size_t)gm << 10) + gn] = v;
      }
}

__device__ void gemm_stream4(const ushort_t* A, const ushort_t* W, int K,
                             const float* bias, ushort_t* outb, float* outf,
                             int act, char* lds, int w, int l, int wm, int wn,
                             int lhi, int llo, int m0, int n0) {
  short* Ab[4] = {(short*)lds, (short*)(lds + 8192), (short*)(lds + 16384),
                  (short*)(lds + 24576)};
  short* Bb[4] = {(short*)(lds + 32768), (short*)(lds + 40960),
                  (short*)(lds + 49152), (short*)(lds + 57344)};
  floatx4 acc[2][2];
#pragma unroll
  for (int i = 0; i < 2; ++i)
#pragma unroll
    for (int j = 0; j < 2; ++j) acc[i][j] = (floatx4){0.f, 0.f, 0.f, 0.f};
  const ushort_t* Abase = A + (size_t)m0 * K;
  const ushort_t* Bbase = W + (size_t)n0 * K;
  int nc = K >> 6;
#pragma unroll
  for (int c0 = 0; c0 < 3; ++c0) {
    stage64(Abase + (c0 << 6), K, Ab[c0], w, l);
    stage64(Bbase + (c0 << 6), K, Bb[c0], w, l);
  }
  for (int c = 0; c < nc; ++c) {
    int nxt = c + 3;
    if (nxt < nc) {
      stage64(Abase + (nxt << 6), K, Ab[nxt & 3], w, l);
      stage64(Bbase + (nxt << 6), K, Bb[nxt & 3], w, l);
      WAITVM(12);
    } else if (nc - c == 3) {
      WAITVM(8);
    } else if (nc - c == 2) {
      WAITVM(4);
    } else {
      WAITVM(0);
    }
    BAR();
    compute_chunk64(Ab[c & 3], Bb[c & 3], acc, wm, wn, lhi, llo);
    BAR();
  }
  ff_epilogue(acc, bias, outb, outf, act, m0, n0, wm, wn, lhi, llo);
}

// Global two-level barrier with full fences.
__device__ __forceinline__ void gbar(unsigned* area, unsigned seq, int t, int bid) {
  __syncthreads();
  if (t == 0) {
    __threadfence();
    unsigned old = atomicAdd(&area[(bid & 15) << 4], 1u);
    if (old == (seq << 4) - 1u) atomicAdd(&area[256], 1u);
    while (__hip_atomic_load(&area[256], __ATOMIC_RELAXED,
                             __HIP_MEMORY_SCOPE_AGENT) < (seq << 4))
      __builtin_amdgcn_s_sleep(1);
    __threadfence();
  }
  __syncthreads();
}

struct KP {
  const float *x, *W1, *b1, *W2, *b2, *Wih, *Whh, *bih, *bhh, *Wa, *ba;
  ushort_t *Xb, *W1b, *W2b, *Wihb, *Whhb, *Wsmb, *X1b, *Xlb, *Hb0, *Hb1;
  float *xw, *bias, *pacc, *probs, *hxout;
  unsigned* barrier;
};

__global__ __launch_bounds__(256, 1) void fused_rnn(KP p) {
  extern __shared__ char lds[];
  cg::grid_group grid = cg::this_grid();
  const int t = threadIdx.x;
  const int w = t >> 6, l = t & 63;
  const int wm = w >> 1, wn = w & 1;
  const int lhi = l >> 4, llo = l & 15;
  const int bid = blockIdx.x;
  const int m0f = (bid >> 4) << 6, n0f = (bid & 15) << 6;
  // RNN mapping: m-group = bid&15 -> all 16 peers share bid%8 (one XCD under
  // round-robin dispatch). Verified at runtime; falls back to sc1 if not.
  const int mgrp = bid & 15, nblk = bid >> 4;
  const int m0r = mgrp << 6, n0r = nblk << 6;
  const int gid = bid * 256 + t;

  // ---- phase 0 ----
  {
    const float4* xf = (const float4*)p.x;
    const float4* w1f = (const float4*)p.W1;
    const float4* w2f = (const float4*)p.W2;
    const float4* wif = (const float4*)p.Wih;
    const float4* whf = (const float4*)p.Whh;
    for (int i = gid; i < 1048576; i += 65536) {
      float4 v = xf[i];
      us4 o;
      o.x = f2bf(v.x); o.y = f2bf(v.y); o.z = f2bf(v.z); o.w = f2bf(v.w);
      ((us4*)p.Xb)[i] = o;
      float4 u = w1f[i];
      o.x = f2bf(u.x); o.y = f2bf(u.y); o.z = f2bf(u.z); o.w = f2bf(u.w);
      ((us4*)p.W1b)[i] = o;
      if (i < 262144) {
        float4 a = w2f[i];
        o.x = f2bf(a.x); o.y = f2bf(a.y); o.z = f2bf(a.z); o.w = f2bf(a.w);
        ((us4*)p.W2b)[i] = o;
        float4 pp = wif[i];
        o.x = f2bf(pp.x); o.y = f2bf(pp.y); o.z = f2bf(pp.z); o.w = f2bf(pp.w);
        ((us4*)p.Wihb)[i] = o;
        float4 q = whf[i];
        o.x = f2bf(q.x); o.y = f2bf(q.y); o.z = f2bf(q.z); o.w = f2bf(q.w);
        ((us4*)p.Whhb)[i] = o;
        o.x = f2bf(pp.x + q.x); o.y = f2bf(pp.y + q.y);
        o.z = f2bf(pp.z + q.z); o.w = f2bf(pp.w + q.w);
        ((us4*)p.Wsmb)[i] = o;
      }
    }
    p.pacc[gid] = 0.f;
    if (gid < 1024) p.bias[gid] = p.bih[gid] + p.bhh[gid];
    if (gid < 4608) p.barrier[gid] = 0u;
  }
  grid.sync();

  // ---- FF phases ----
  gemm_stream4(p.Xb, p.W1b, 4096, p.b1, p.X1b, nullptr, 0, lds, w, l, wm, wn,
               lhi, llo, m0f, n0f);
  gbar(p.barrier, 1, t, bid);
  gemm_stream4(p.X1b, p.W2b, 1024, p.b2, p.Xlb, nullptr, 0, lds, w, l, wm, wn,
               lhi, llo, m0f, n0f);
  gbar(p.barrier, 2, t, bid);
  gemm_stream4(p.Xlb, p.Wihb, 1024, nullptr, nullptr, p.xw, 2, lds, w, l, wm,
               wn, lhi, llo, m0f, n0f);
  gbar(p.barrier, 3, t, bid);

  // ---- publish XCD id ----
  unsigned xccid;
  __asm__ __volatile__("s_getreg_b32 %0, hwreg(HW_REG_XCC_ID)" : "=s"(xccid));
  if (t == 0)
    __hip_atomic_store(&p.barrier[1024 + (mgrp << 4) + nblk],
                       1000u + (xccid & 15u), __ATOMIC_RELAXED,
                       __HIP_MEMORY_SCOPE_AGENT);

  // ---- resident FULL Wsum slab (rows n0r..n0r+63, K=1024, 128 KB) ----
  short* slab = (short*)lds;
  {
    const ushort_t* Wn = p.Wsmb + ((size_t)n0r << 10);
#pragma unroll
    for (int i = 0; i < 32; ++i) {
      int c = t + (i << 8);
      int r = c >> 7, cc = c & 127;
      int pc = (cc & ~7) | ((cc & 7) ^ (r & 7));
      short8 v = *(const short8*)(Wn + ((size_t)r << 10) + (cc << 3));
      *(short8*)(slab + (r << 10) + (pc << 3)) = v;
    }
  }
  gbar(p.barrier, 4, t, bid);

  // ---- m-group locality check ----
  unsigned myx = 0u;
  if (l < 16)
    myx = __hip_atomic_load(&p.barrier[1024 + (mgrp << 4) + l],
                            __ATOMIC_RELAXED, __HIP_MEMORY_SCOPE_AGENT);
  unsigned x0 = __shfl(myx, 0);
  const bool local = __all((l >= 16) || (myx == x0));

  ushort_t* Hb[2] = {p.Hb0, p.Hb1};
  unsigned* mbar = p.barrier + 320 + (mgrp << 4);

  int gnb[2], gmv[2];
#pragma unroll
  for (int tn = 0; tn < 2; ++tn)
    gnb[tn] = n0r + (wn << 5) + (tn << 4) + (lhi << 2);
#pragma unroll
  for (int tm = 0; tm < 2; ++tm)
    gmv[tm] = m0r + (wm << 5) + (tm << 4) + llo;
  float bias_r[2][4], wa_r[2][4], xw_r[2][2][4];
#pragma unroll
  for (int tn = 0; tn < 2; ++tn)
#pragma unroll
    for (int i = 0; i < 4; ++i) {
      bias_r[tn][i] = p.bias[gnb[tn] + i];
      wa_r[tn][i] = p.Wa[gnb[tn] + i];
    }
#pragma unroll
  for (int tm = 0; tm < 2; ++tm)
#pragma unroll
    for (int tn = 0; tn < 2; ++tn)
#pragma unroll
      for (int i = 0; i < 4; ++i)
        xw_r[tm][tn][i] = p.xw[((size_t)gmv[tm] << 10) + gnb[tn] + i];

  const float ba0 = p.ba[0];
  // per-lane constant parts of fragment addresses
  const int hrowoff = (((wm << 5) + llo) << 10) + (lhi << 3);
  const ushort_t* wb0 =
      p.Whhb + ((size_t)(n0r + (wn << 5) + llo) << 10) + (lhi << 3);
  const ushort_t* wb1 = wb0 + (16 << 10);

  auto loadA = [&](short8 dst[2], int c) {
    int u = (c << 2) + lhi;
#pragma unroll
    for (int tn = 0; tn < 2; ++tn) {
      int na = (wn << 5) + (tn << 4) + llo;
      int pu = (u & ~7) | ((u & 7) ^ (na & 7));
      dst[tn] = *(const short8*)(slab + (na << 10) + (pu << 3));
    }
  };

  auto runsteps = [&](auto LC) {
    constexpr bool SYS = (decltype(LC)::value == 0);
    for (int st = 0; st < 64; ++st) {
      const ushort_t* hbase =
          ((st == 0) ? p.Xlb : Hb[st & 1]) + ((size_t)m0r << 10);
      const ushort_t* hb0 = hbase + hrowoff;
      const ushort_t* hb1 = hb0 + (16 << 10);
      bool flag = st && !(st & 15);
      floatx4 acc[2][2];  // [tn][tm]
#pragma unroll
      for (int i = 0; i < 2; ++i)
#pragma unroll
        for (int j = 0; j < 2; ++j) acc[i][j] = (floatx4){0.f, 0.f, 0.f, 0.f};

      if (!flag) {
        short8 hreg[8][2];
        static_for<6>([&](auto ij) {
          constexpr int j = decltype(ij)::value;
          ldh<SYS, j * 64>(hreg[j][0], hb0);
          ldh<SYS, j * 64>(hreg[j][1], hb1);
        });
        short8 aR[3][2];
        loadA(aR[0], 0);
        loadA(aR[1], 1);
        static_for<32>([&](auto ic) {
          constexpr int c = decltype(ic)::value;
          if constexpr (c + 6 < 32) {
            ldh<SYS, (c + 6) * 64>(hreg[(c + 6) & 7][0], hb0);
            ldh<SYS, (c + 6) * 64>(hreg[(c + 6) & 7][1], hb1);
          }
          waitvm<nh(c)>();
          RB2(hreg[c & 7][0], hreg[c & 7][1]);
          if (c + 2 < 32) loadA(aR[(c + 2) % 3], c + 2);
#pragma unroll
          for (int tn = 0; tn < 2; ++tn)
#pragma unroll
            for (int tm = 0; tm < 2; ++tm)
              acc[tn][tm] = __builtin_amdgcn_mfma_f32_16x16x32_bf16(
                  aR[c % 3][tn], hreg[c & 7][tm], acc[tn][tm], 0, 0, 0);
        });
      } else {
        short8 hreg[8][2], wreg[8][2];
        static_for<6>([&](auto ij) {
          constexpr int j = decltype(ij)::value;
          ldh<SYS, j * 64>(hreg[j][0], hb0);
          ldh<SYS, j * 64>(hreg[j][1], hb1);
          ldw<j * 64>(wreg[j][0], wb0);
          ldw<j * 64>(wreg[j][1], wb1);
        });
        static_for<32>([&](auto ic) {
          constexpr int c = decltype(ic)::value;
          if constexpr (c + 6 < 32) {
            ldh<SYS, (c + 6) * 64>(hreg[(c + 6) & 7][0], hb0);
            ldh<SYS, (c + 6) * 64>(hreg[(c + 6) & 7][1], hb1);
            ldw<(c + 6) * 64>(wreg[(c + 6) & 7][0], wb0);
            ldw<(c + 6) * 64>(wreg[(c + 6) & 7][1], wb1);
          }
          waitvm<nf(c)>();
          RB2(hreg[c & 7][0], hreg[c & 7][1]);
          RB2(wreg[c & 7][0], wreg[c & 7][1]);
#pragma unroll
          for (int tn = 0; tn < 2; ++tn)
#pragma unroll
            for (int tm = 0; tm < 2; ++tm)
              acc[tn][tm] = __builtin_amdgcn_mfma_f32_16x16x32_bf16(
                  wreg[c & 7][tn], hreg[c & 7][tm], acc[tn][tm], 0, 0, 0);
        });
      }

      // ---- epilogue ----
      bool last = (st == 63);
      ushort_t* Hnext = Hb[(st + 1) & 1];
      float hv[2][2][4];  // [tn][tm][i]
#pragma unroll
      for (int tn = 0; tn < 2; ++tn)
#pragma unroll
        for (int tm = 0; tm < 2; ++tm)
#pragma unroll
          for (int i = 0; i < 4; ++i) {
            float v = acc[tn][tm][i] + bias_r[tn][i];
            if (flag) v += xw_r[tm][tn][i];
            hv[tn][tm][i] = fast_tanh(v);
          }
      if (!last) {
#pragma unroll
        for (int tn = 0; tn < 2; ++tn)
#pragma unroll
          for (int tm = 0; tm < 2; ++tm) {
            unsigned long long pk =
                (unsigned long long)f2bf(hv[tn][tm][0]) |
                ((unsigned long long)f2bf(hv[tn][tm][1]) << 16) |
                ((unsigned long long)f2bf(hv[tn][tm][2]) << 32) |
                ((unsigned long long)f2bf(hv[tn][tm][3]) << 48);
            ushort_t* dst = Hnext + ((size_t)gmv[tm] << 10) + gnb[tn];
            if (!SYS) {
              __asm__ __volatile__("global_store_dwordx2 %0, %1, off"
                                   :
                                   : "v"(dst), "v"(pk)
                                   : "memory");
            } else {
              __asm__ __volatile__("global_store_dwordx2 %0, %1, off sc0 sc1"
                                   :
                                   : "v"(dst), "v"(pk)
                                   : "memory");
            }
          }
      } else {
#pragma unroll
        for (int tn = 0; tn < 2; ++tn)
#pragma unroll
          for (int tm = 0; tm < 2; ++tm) {
            float4 o = make_float4(hv[tn][tm][0], hv[tn][tm][1], hv[tn][tm][2],
                                   hv[tn][tm][3]);
            *(float4*)(p.hxout + ((size_t)gmv[tm] << 10) + gnb[tn]) = o;
          }
      }
#pragma unroll
      for (int tm = 0; tm < 2; ++tm) {
        float s = 0.f;
#pragma unroll
        for (int tn = 0; tn < 2; ++tn)
#pragma unroll
          for (int i = 0; i < 4; ++i) s += hv[tn][tm][i] * wa_r[tn][i];
        s += __shfl_xor(s, 16);
        s += __shfl_xor(s, 32);
        if (l < 16) atomicAdd(&p.pacc[(st << 10) + gmv[tm]], s);
      }

      // ---- m-group barrier ----
      if (!last) {
        WAITVM(0);
        __syncthreads();
        if (t == 0) {
          atomicAdd(mbar, 1u);
          unsigned tgt = (unsigned)(st + 1) << 4;
          while (__hip_atomic_load(mbar, __ATOMIC_RELAXED,
                                   __HIP_MEMORY_SCOPE_AGENT) < tgt)
            __builtin_amdgcn_s_sleep(1);
        }
        __syncthreads();
      } else {
        WAITVM(0);
      }
    }
  };
  if (local) runsteps(Int<1>{});
  else runsteps(Int<0>{});

  gbar(p.barrier, 5, t, bid);
  p.probs[gid] = fast_sigmoid(p.pacc[gid] + ba0);
}

extern "C" void kernel_launch(void* const* d_in, const int* in_sizes, int n_in,
                              void* d_out, int out_size, void* d_ws,
                              size_t ws_size, hipStream_t stream) {
  char* ws = (char*)d_ws;
  KP p;
  p.x = (const float*)d_in[0];
  p.W1 = (const float*)d_in[1];
  p.b1 = (const float*)d_in[2];
  p.W2 = (const float*)d_in[3];
  p.b2 = (const float*)d_in[4];
  p.Wih = (const float*)d_in[5];
  p.Whh = (const float*)d_in[6];
  p.bih = (const float*)d_in[7];
  p.bhh = (const float*)d_in[8];
  p.Wa = (const float*)d_in[9];
  p.ba = (const float*)d_in[10];
  p.Xb = (ushort_t*)(ws);
  p.W1b = (ushort_t*)(ws + ((size_t)8 << 20));
  p.W2b = (ushort_t*)(ws + ((size_t)16 << 20));
  p.Wihb = (ushort_t*)(ws + ((size_t)18 << 20));
  p.Whhb = (ushort_t*)(ws + ((size_t)20 << 20));
  p.Wsmb = (ushort_t*)(ws + ((size_t)22 << 20));
  p.X1b = (ushort_t*)(ws + ((size_t)24 << 20));
  p.Xlb = (ushort_t*)(ws + ((size_t)26 << 20));
  p.Hb0 = (ushort_t*)(ws + ((size_t)28 << 20));
  p.Hb1 = (ushort_t*)(ws + ((size_t)30 << 20));
  p.xw = (float*)(ws + ((size_t)32 << 20));
  p.bias = (float*)(ws + ((size_t)36 << 20));
  p.pacc = (float*)(ws + ((size_t)36 << 20) + 4096);
  p.barrier = (unsigned*)(ws + ((size_t)36 << 20) + 4096 + 262144);
  p.probs = (float*)d_out;
  p.hxout = (float*)d_out + 65536;

  (void)hipFuncSetAttribute((const void*)fused_rnn,
                            hipFuncAttributeMaxDynamicSharedMemorySize, 131072);
  void* args[] = {&p};
  (void)hipLaunchCooperativeKernel((const void*)fused_rnn, dim3(256), dim3(256),
                                   args, 131072, stream);
}

// Round 11
// 659.062 us; speedup vs baseline: 1.3702x; 1.3702x over previous
//
#include <hip/hip_runtime.h>
#include <hip/hip_cooperative_groups.h>

namespace cg = cooperative_groups;

typedef unsigned short ushort_t;
typedef __attribute__((ext_vector_type(8))) short short8;
typedef __attribute__((ext_vector_type(4))) float floatx4;
typedef __attribute__((ext_vector_type(4))) ushort_t us4;

#define BAR() __builtin_amdgcn_s_barrier()
#define WAITVM(n) \
  __builtin_amdgcn_s_waitcnt(0x0F70 | ((n) & 15) | (((n) >> 4) << 14))
#define CBARRIER() __asm__ __volatile__("" ::: "memory")

template <int N>
__device__ __forceinline__ void waitvm() {
  __builtin_amdgcn_s_waitcnt(0x0F70 | (N & 15) | ((N >> 4) << 14));
}

template <int V> struct Int { static constexpr int value = V; };
template <int C, int N, typename F> struct StaticFor {
  __device__ __forceinline__ static void run(F& f) {
    f(Int<C>{});
    StaticFor<C + 1, N, F>::run(f);
  }
};
template <int N, typename F> struct StaticFor<N, N, F> {
  __device__ __forceinline__ static void run(F&) {}
};
template <int N, typename F>
__device__ __forceinline__ void static_for(F&& f) {
  StaticFor<0, N, F>::run(f);
}

// private h ring (3 slots, distance 2, 2 loads/chunk)
constexpr int nwp(int c) { return c <= 29 ? 4 : (c == 30 ? 2 : 0); }
// flag path paired ring depth 2 (round-8)
constexpr int nwb(int c) { return (c == 31) ? 0 : 2; }

__device__ __forceinline__ ushort_t f2bf(float f) {
  union { float f; unsigned u; } v; v.f = f;
  unsigned r = v.u + 0x7fffu + ((v.u >> 16) & 1u);
  return (ushort_t)(r >> 16);
}
__device__ __forceinline__ float fast_sigmoid(float x) {
  return 1.f / (1.f + __expf(-x));
}
__device__ __forceinline__ float fast_tanh(float x) {
  return 1.f - 2.f / (__expf(2.f * x) + 1.f);
}

template <int AUX>
__device__ __forceinline__ void gld16x(const void* g, void* l) {
  __builtin_amdgcn_global_load_lds(
      (__attribute__((address_space(1))) void*)g,
      (__attribute__((address_space(3))) void*)l, 16, 0, AUX);
}

// wave-private stage: 32 rows x 32 k (2KB) into slot; 2 gld16, offset baked
// into the GLOBAL pointers (offset arg stays 0 — non-zero offset arg was the
// round-10 NaN suspect).
template <int AUX>
__device__ __forceinline__ void stage_priv(const ushort_t* b0,
                                           const ushort_t* b1, short* slot) {
  gld16x<AUX>(b0, slot);
  gld16x<AUX>(b1, slot + 512);
}

// ---- FF staging: 64x64 chunk, 8KB, XOR-8 swizzle ----
__device__ __forceinline__ void stage64(const ushort_t* src, int ldk,
                                        short* dst, int w, int l) {
  int r0 = (w << 3) + (l >> 3);
  int cb0 = (l & 7) ^ (r0 & 7);
  int r1 = 32 + r0;
  int cb1 = (l & 7) ^ (r1 & 7);
  gld16x<0>(src + (size_t)r0 * ldk + (cb0 << 3), dst + (w << 9));
  gld16x<0>(src + (size_t)r1 * ldk + (cb1 << 3), dst + 2048 + (w << 9));
}

// RNN 64-row chunk staging (flag path): 64 rows x 32 k (4KB), block-coop.
template <int AUX>
__device__ __forceinline__ void stage_chunk(const ushort_t* src, short* slot,
                                            int w, int l) {
  int pu = (w << 6) + l;
  int r = pu >> 2;
  int sg = (pu & 3) ^ ((r >> 1) & 3);
  gld16x<AUX>(src + ((size_t)r << 10) + (sg << 3), slot + (w << 9));
}

__device__ __forceinline__ void compute_chunk64(const short* As, const short* Bs,
                                                floatx4 acc[2][2], int wm,
                                                int wn, int lhi, int llo) {
#pragma unroll
  for (int ks = 0; ks < 2; ++ks) {
    short8 a[2], b[2];
#pragma unroll
    for (int tm = 0; tm < 2; ++tm) {
      int m = (wm << 5) + (tm << 4) + llo;
      int ph = ((ks << 2) + lhi) ^ (m & 7);
      a[tm] = *(const short8*)(As + m * 64 + (ph << 3));
    }
#pragma unroll
    for (int tn = 0; tn < 2; ++tn) {
      int n = (wn << 5) + (tn << 4) + llo;
      int ph = ((ks << 2) + lhi) ^ (n & 7);
      b[tn] = *(const short8*)(Bs + n * 64 + (ph << 3));
    }
#pragma unroll
    for (int tm = 0; tm < 2; ++tm)
#pragma unroll
      for (int tn = 0; tn < 2; ++tn)
        acc[tm][tn] = __builtin_amdgcn_mfma_f32_16x16x32_bf16(
            a[tm], b[tn], acc[tm][tn], 0, 0, 0);
  }
}

__device__ __forceinline__ void ff_epilogue(floatx4 acc[2][2], const float* bias,
                                            ushort_t* outb, float* outf, int act,
                                            int m0, int n0, int wm, int wn,
                                            int lhi, int llo) {
#pragma unroll
  for (int tm = 0; tm < 2; ++tm)
#pragma unroll
    for (int tn = 0; tn < 2; ++tn)
#pragma unroll
      for (int i = 0; i < 4; ++i) {
        int gm = m0 + (wm << 5) + (tm << 4) + (lhi << 2) + i;
        int gn = n0 + (wn << 5) + (tn << 4) + llo;
        float v = acc[tm][tn][i];
        if (bias) v += bias[gn];
        if (act == 0) v = fmaxf(v, 0.f);
        if (outb) outb[((size_t)gm << 10) + gn] = f2bf(v);
        if (outf) outf[((size_t)gm << 10) + gn] = v;
      }
}

__device__ void gemm_stream4(const ushort_t* A, const ushort_t* W, int K,
                             const float* bias, ushort_t* outb, float* outf,
                             int act, char* lds, int w, int l, int wm, int wn,
                             int lhi, int llo, int m0, int n0) {
  short* Ab[4] = {(short*)lds, (short*)(lds + 8192), (short*)(lds + 16384),
                  (short*)(lds + 24576)};
  short* Bb[4] = {(short*)(lds + 32768), (short*)(lds + 40960),
                  (short*)(lds + 49152), (short*)(lds + 57344)};
  floatx4 acc[2][2];
#pragma unroll
  for (int i = 0; i < 2; ++i)
#pragma unroll
    for (int j = 0; j < 2; ++j) acc[i][j] = (floatx4){0.f, 0.f, 0.f, 0.f};
  const ushort_t* Abase = A + (size_t)m0 * K;
  const ushort_t* Bbase = W + (size_t)n0 * K;
  int nc = K >> 6;
#pragma unroll
  for (int c0 = 0; c0 < 3; ++c0) {
    stage64(Abase + (c0 << 6), K, Ab[c0], w, l);
    stage64(Bbase + (c0 << 6), K, Bb[c0], w, l);
  }
  for (int c = 0; c < nc; ++c) {
    int nxt = c + 3;
    if (nxt < nc) {
      stage64(Abase + (nxt << 6), K, Ab[nxt & 3], w, l);
      stage64(Bbase + (nxt << 6), K, Bb[nxt & 3], w, l);
      WAITVM(12);
    } else if (nc - c == 3) {
      WAITVM(8);
    } else if (nc - c == 2) {
      WAITVM(4);
    } else {
      WAITVM(0);
    }
    BAR();
    CBARRIER();
    compute_chunk64(Ab[c & 3], Bb[c & 3], acc, wm, wn, lhi, llo);
    BAR();
  }
  ff_epilogue(acc, bias, outb, outf, act, m0, n0, wm, wn, lhi, llo);
}

// Global two-level barrier with full fences.
__device__ __forceinline__ void gbar(unsigned* area, unsigned seq, int t, int bid) {
  __syncthreads();
  if (t == 0) {
    __threadfence();
    unsigned old = atomicAdd(&area[(bid & 15) << 4], 1u);
    if (old == (seq << 4) - 1u) atomicAdd(&area[256], 1u);
    while (__hip_atomic_load(&area[256], __ATOMIC_RELAXED,
                             __HIP_MEMORY_SCOPE_AGENT) < (seq << 4))
      __builtin_amdgcn_s_sleep(1);
    __threadfence();
  }
  __syncthreads();
}

struct KP {
  const float *x, *W1, *b1, *W2, *b2, *Wih, *Whh, *bih, *bhh, *Wa, *ba;
  ushort_t *Xb, *W1b, *W2b, *Wihb, *Whhb, *Wsmb, *X1b, *Xlb, *Hb0, *Hb1;
  float *xw, *bias, *pacc, *probs, *hxout;
  unsigned* barrier;
};

__global__ __launch_bounds__(256, 1) void fused_rnn(KP p) {
  extern __shared__ char lds[];
  cg::grid_group grid = cg::this_grid();
  const int t = threadIdx.x;
  const int w = t >> 6, l = t & 63;
  const int wm = w >> 1, wn = w & 1;
  const int lhi = l >> 4, llo = l & 15;
  const int bid = blockIdx.x;
  const int m0f = (bid >> 4) << 6, n0f = (bid & 15) << 6;
  // RNN mapping: m-group = bid&15 -> all 16 peers share bid%8 (one XCD under
  // round-robin dispatch). Verified at runtime; falls back to sc1 if not.
  const int mgrp = bid & 15, nblk = bid >> 4;
  const int m0r = mgrp << 6, n0r = nblk << 6;
  const int gid = bid * 256 + t;

  // ---- phase 0 ----
  {
    const float4* xf = (const float4*)p.x;
    const float4* w1f = (const float4*)p.W1;
    const float4* w2f = (const float4*)p.W2;
    const float4* wif = (const float4*)p.Wih;
    const float4* whf = (const float4*)p.Whh;
    for (int i = gid; i < 1048576; i += 65536) {
      float4 v = xf[i];
      us4 o;
      o.x = f2bf(v.x); o.y = f2bf(v.y); o.z = f2bf(v.z); o.w = f2bf(v.w);
      ((us4*)p.Xb)[i] = o;
      float4 u = w1f[i];
      o.x = f2bf(u.x); o.y = f2bf(u.y); o.z = f2bf(u.z); o.w = f2bf(u.w);
      ((us4*)p.W1b)[i] = o;
      if (i < 262144) {
        float4 a = w2f[i];
        o.x = f2bf(a.x); o.y = f2bf(a.y); o.z = f2bf(a.z); o.w = f2bf(a.w);
        ((us4*)p.W2b)[i] = o;
        float4 pp = wif[i];
        o.x = f2bf(pp.x); o.y = f2bf(pp.y); o.z = f2bf(pp.z); o.w = f2bf(pp.w);
        ((us4*)p.Wihb)[i] = o;
        float4 q = whf[i];
        o.x = f2bf(q.x); o.y = f2bf(q.y); o.z = f2bf(q.z); o.w = f2bf(q.w);
        ((us4*)p.Whhb)[i] = o;
        o.x = f2bf(pp.x + q.x); o.y = f2bf(pp.y + q.y);
        o.z = f2bf(pp.z + q.z); o.w = f2bf(pp.w + q.w);
        ((us4*)p.Wsmb)[i] = o;
      }
    }
    p.pacc[gid] = 0.f;
    if (gid < 1024) p.bias[gid] = p.bih[gid] + p.bhh[gid];
    if (gid < 4608) p.barrier[gid] = 0u;
  }
  grid.sync();

  // ---- FF phases ----
  gemm_stream4(p.Xb, p.W1b, 4096, p.b1, p.X1b, nullptr, 0, lds, w, l, wm, wn,
               lhi, llo, m0f, n0f);
  gbar(p.barrier, 1, t, bid);
  gemm_stream4(p.X1b, p.W2b, 1024, p.b2, p.Xlb, nullptr, 0, lds, w, l, wm, wn,
               lhi, llo, m0f, n0f);
  gbar(p.barrier, 2, t, bid);
  gemm_stream4(p.Xlb, p.Wihb, 1024, nullptr, nullptr, p.xw, 2, lds, w, l, wm,
               wn, lhi, llo, m0f, n0f);
  gbar(p.barrier, 3, t, bid);

  // ---- publish XCD id ----
  unsigned xccid;
  __asm__ __volatile__("s_getreg_b32 %0, hwreg(HW_REG_XCC_ID)" : "=s"(xccid));
  if (t == 0)
    __hip_atomic_store(&p.barrier[1024 + (mgrp << 4) + nblk],
                       1000u + (xccid & 15u), __ATOMIC_RELAXED,
                       __HIP_MEMORY_SCOPE_AGENT);

  // ---- resident FULL Wsum slab (rows n0r..n0r+63, K=1024, 128 KB) ----
  short* slab = (short*)lds;
  {
    const ushort_t* Wn = p.Wsmb + ((size_t)n0r << 10);
#pragma unroll
    for (int i = 0; i < 32; ++i) {
      int c = t + (i << 8);
      int r = c >> 7, cc = c & 127;
      int pc = (cc & ~7) | ((cc & 7) ^ (r & 7));
      short8 v = *(const short8*)(Wn + ((size_t)r << 10) + (cc << 3));
      *(short8*)(slab + (r << 10) + (pc << 3)) = v;
    }
  }
  gbar(p.barrier, 4, t, bid);

  // ---- m-group locality check ----
  unsigned myx = 0u;
  if (l < 16)
    myx = __hip_atomic_load(&p.barrier[1024 + (mgrp << 4) + l],
                            __ATOMIC_RELAXED, __HIP_MEMORY_SCOPE_AGENT);
  unsigned x0 = __shfl(myx, 0);
  const bool local = __all((l >= 16) || (myx == x0));

  // LDS after slab: 24KB region.
  //  non-flag: wave-private h rings, wave w at +w*6KB, 3 slots x 2KB
  //  flag:     block-coop 6 x 4KB ring (separated by step-end syncthreads)
  short* priv = (short*)(lds + 131072) + w * 3072;
  short* ring = (short*)(lds + 131072);
  ushort_t* Hb[2] = {p.Hb0, p.Hb1};
  unsigned* mbar = p.barrier + 320 + (mgrp << 4);

  int gnb[2], gmv[2];
#pragma unroll
  for (int tn = 0; tn < 2; ++tn)
    gnb[tn] = n0r + (wn << 5) + (tn << 4) + (lhi << 2);
#pragma unroll
  for (int tm = 0; tm < 2; ++tm)
    gmv[tm] = m0r + (wm << 5) + (tm << 4) + llo;
  float bias_r[2][4], wa_r[2][4], xw_r[2][2][4];
#pragma unroll
  for (int tn = 0; tn < 2; ++tn)
#pragma unroll
    for (int i = 0; i < 4; ++i) {
      bias_r[tn][i] = p.bias[gnb[tn] + i];
      wa_r[tn][i] = p.Wa[gnb[tn] + i];
    }
#pragma unroll
  for (int tm = 0; tm < 2; ++tm)
#pragma unroll
    for (int tn = 0; tn < 2; ++tn)
#pragma unroll
      for (int i = 0; i < 4; ++i)
        xw_r[tm][tn][i] = p.xw[((size_t)gmv[tm] << 10) + gnb[tn] + i];

  const float ba0 = p.ba[0];
  // private-stage per-lane source offsets (within this wave's 32 h rows)
  const int prow = (wm << 5) + (l >> 2);           // j=0 rows
  const int pseg = (l & 3) ^ ((l >> 3) & 3);
  const int poff0 = (prow << 10) + (pseg << 3);    // shorts
  const int poff1 = poff0 + (16 << 10);            // +16 rows
  // private-slot read offsets (B-fragment), step-invariant
  int offb[2];
#pragma unroll
  for (int tm = 0; tm < 2; ++tm) {
    int rl = (tm << 4) + llo;
    offb[tm] = rl * 32 + ((lhi ^ ((rl >> 1) & 3)) << 3);
  }
  short* ps[3] = {priv, priv + 1024, priv + 2048};

  auto runsteps = [&](auto LC) {
    constexpr bool LOCAL = (decltype(LC)::value != 0);
    constexpr int AUXH = LOCAL ? 1 : 17;  // sc0 (L2-local) vs sc0|sc1 (MALL)
    for (int st = 0; st < 64; ++st) {
      const ushort_t* hbase =
          ((st == 0) ? p.Xlb : Hb[st & 1]) + ((size_t)m0r << 10);
      bool flag = st && !(st & 15);
      floatx4 acc[2][2];  // [tn][tm]
#pragma unroll
      for (int i = 0; i < 2; ++i)
#pragma unroll
        for (int j = 0; j < 2; ++j) acc[i][j] = (floatx4){0.f, 0.f, 0.f, 0.f};

      if (!flag) {
        // wave-private h staging: zero intra-loop barriers
        const ushort_t* hp0 = hbase + poff0;
        const ushort_t* hp1 = hbase + poff1;
        stage_priv<AUXH>(hp0, hp1, ps[0]);
        stage_priv<AUXH>(hp0 + 32, hp1 + 32, ps[1]);
        static_for<32>([&](auto ic) {
          constexpr int c = decltype(ic)::value;
          if constexpr (c + 2 < 32)
            stage_priv<AUXH>(hp0 + ((c + 2) << 5), hp1 + ((c + 2) << 5),
                             ps[(c + 2) % 3]);
          waitvm<nwp(c)>();
          CBARRIER();
          const short* hs = ps[c % 3];
          short8 afr[2], bfr[2];
#pragma unroll
          for (int tn = 0; tn < 2; ++tn) {
            int na = (wn << 5) + (tn << 4) + llo;
            int u = (c << 2) + lhi;
            int pu = (u & ~7) | ((u & 7) ^ (na & 7));
            afr[tn] = *(const short8*)(slab + (na << 10) + (pu << 3));
          }
#pragma unroll
          for (int tm = 0; tm < 2; ++tm)
            bfr[tm] = *(const short8*)(hs + offb[tm]);
#pragma unroll
          for (int tn = 0; tn < 2; ++tn)
#pragma unroll
            for (int tm = 0; tm < 2; ++tm)
              acc[tn][tm] = __builtin_amdgcn_mfma_f32_16x16x32_bf16(
                  afr[tn], bfr[tm], acc[tn][tm], 0, 0, 0);
        });
      } else {
        // block-coop W+h staging (round-8 proven), 3 steps only
        const ushort_t* wbase = p.Whhb + ((size_t)n0r << 10);
#pragma unroll
        for (int j = 0; j < 2; ++j) {
          stage_chunk<0>(wbase + (j << 5), ring + j * 2048, w, l);
          stage_chunk<AUXH>(hbase + (j << 5), ring + (3 + j) * 2048, w, l);
        }
        static_for<32>([&](auto icc) {
          constexpr int c = decltype(icc)::value;
          waitvm<nwb(c)>();
          BAR();
          CBARRIER();
          if (c + 2 < 32) {
            stage_chunk<0>(wbase + ((c + 2) << 5), ring + ((c + 2) % 3) * 2048,
                           w, l);
            stage_chunk<AUXH>(hbase + ((c + 2) << 5),
                              ring + (3 + (c + 2) % 3) * 2048, w, l);
          }
          const short* wslot = ring + (c % 3) * 2048;
          const short* hslot = ring + (3 + c % 3) * 2048;
          short8 afr[2], bfr[2];
#pragma unroll
          for (int tn = 0; tn < 2; ++tn) {
            int na = (wn << 5) + (tn << 4) + llo;
            afr[tn] = *(const short8*)(wslot + na * 32 +
                                       ((lhi ^ ((na >> 1) & 3)) << 3));
          }
#pragma unroll
          for (int tm = 0; tm < 2; ++tm) {
            int mb = (wm << 5) + (tm << 4) + llo;
            bfr[tm] = *(const short8*)(hslot + mb * 32 +
                                       ((lhi ^ ((mb >> 1) & 3)) << 3));
          }
#pragma unroll
          for (int tn = 0; tn < 2; ++tn)
#pragma unroll
            for (int tm = 0; tm < 2; ++tm)
              acc[tn][tm] = __builtin_amdgcn_mfma_f32_16x16x32_bf16(
                  afr[tn], bfr[tm], acc[tn][tm], 0, 0, 0);
        });
      }

      // ---- epilogue ----
      bool last = (st == 63);
      ushort_t* Hnext = Hb[(st + 1) & 1];
      float hv[2][2][4];  // [tn][tm][i]
#pragma unroll
      for (int tn = 0; tn < 2; ++tn)
#pragma unroll
        for (int tm = 0; tm < 2; ++tm)
#pragma unroll
          for (int i = 0; i < 4; ++i) {
            float v = acc[tn][tm][i] + bias_r[tn][i];
            if (flag) v += xw_r[tm][tn][i];
            hv[tn][tm][i] = fast_tanh(v);
          }
      if (!last) {
#pragma unroll
        for (int tn = 0; tn < 2; ++tn)
#pragma unroll
          for (int tm = 0; tm < 2; ++tm) {
            unsigned long long pk =
                (unsigned long long)f2bf(hv[tn][tm][0]) |
                ((unsigned long long)f2bf(hv[tn][tm][1]) << 16) |
                ((unsigned long long)f2bf(hv[tn][tm][2]) << 32) |
                ((unsigned long long)f2bf(hv[tn][tm][3]) << 48);
            ushort_t* dst = Hnext + ((size_t)gmv[tm] << 10) + gnb[tn];
            if (LOCAL) {
              __asm__ __volatile__("global_store_dwordx2 %0, %1, off"
                                   :
                                   : "v"(dst), "v"(pk)
                                   : "memory");
            } else {
              __asm__ __volatile__("global_store_dwordx2 %0, %1, off sc0 sc1"
                                   :
                                   : "v"(dst), "v"(pk)
                                   : "memory");
            }
          }
      } else {
#pragma unroll
        for (int tn = 0; tn < 2; ++tn)
#pragma unroll
          for (int tm = 0; tm < 2; ++tm) {
            float4 o = make_float4(hv[tn][tm][0], hv[tn][tm][1], hv[tn][tm][2],
                                   hv[tn][tm][3]);
            *(float4*)(p.hxout + ((size_t)gmv[tm] << 10) + gnb[tn]) = o;
          }
      }
#pragma unroll
      for (int tm = 0; tm < 2; ++tm) {
        float s = 0.f;
#pragma unroll
        for (int tn = 0; tn < 2; ++tn)
#pragma unroll
          for (int i = 0; i < 4; ++i) s += hv[tn][tm][i] * wa_r[tn][i];
        s += __shfl_xor(s, 16);
        s += __shfl_xor(s, 32);
        if (l < 16) atomicAdd(&p.pacc[(st << 10) + gmv[tm]], s);
      }

      // ---- m-group barrier ----
      if (!last) {
        WAITVM(0);
        __syncthreads();
        if (t == 0) {
          atomicAdd(mbar, 1u);
          unsigned tgt = (unsigned)(st + 1) << 4;
          while (__hip_atomic_load(mbar, __ATOMIC_RELAXED,
                                   __HIP_MEMORY_SCOPE_AGENT) < tgt)
            __builtin_amdgcn_s_sleep(1);
        }
        __syncthreads();
      } else {
        WAITVM(0);
      }
    }
  };
  if (local) runsteps(Int<1>{});
  else runsteps(Int<0>{});

  gbar(p.barrier, 5, t, bid);
  p.probs[gid] = fast_sigmoid(p.pacc[gid] + ba0);
}

extern "C" void kernel_launch(void* const* d_in, const int* in_sizes, int n_in,
                              void* d_out, int out_size, void* d_ws,
                              size_t ws_size, hipStream_t stream) {
  char* ws = (char*)d_ws;
  KP p;
  p.x = (const float*)d_in[0];
  p.W1 = (const float*)d_in[1];
  p.b1 = (const float*)d_in[2];
  p.W2 = (const float*)d_in[3];
  p.b2 = (const float*)d_in[4];
  p.Wih = (const float*)d_in[5];
  p.Whh = (const float*)d_in[6];
  p.bih = (const float*)d_in[7];
  p.bhh = (const float*)d_in[8];
  p.Wa = (const float*)d_in[9];
  p.ba = (const float*)d_in[10];
  p.Xb = (ushort_t*)(ws);
  p.W1b = (ushort_t*)(ws + ((size_t)8 << 20));
  p.W2b = (ushort_t*)(ws + ((size_t)16 << 20));
  p.Wihb = (ushort_t*)(ws + ((size_t)18 << 20));
  p.Whhb = (ushort_t*)(ws + ((size_t)20 << 20));
  p.Wsmb = (ushort_t*)(ws + ((size_t)22 << 20));
  p.X1b = (ushort_t*)(ws + ((size_t)24 << 20));
  p.Xlb = (ushort_t*)(ws + ((size_t)26 << 20));
  p.Hb0 = (ushort_t*)(ws + ((size_t)28 << 20));
  p.Hb1 = (ushort_t*)(ws + ((size_t)30 << 20));
  p.xw = (float*)(ws + ((size_t)32 << 20));
  p.bias = (float*)(ws + ((size_t)36 << 20));
  p.pacc = (float*)(ws + ((size_t)36 << 20) + 4096);
  p.barrier = (unsigned*)(ws + ((size_t)36 << 20) + 4096 + 262144);
  p.probs = (float*)d_out;
  p.hxout = (float*)d_out + 65536;

  (void)hipFuncSetAttribute((const void*)fused_rnn,
                            hipFuncAttributeMaxDynamicSharedMemorySize, 155648);
  void* args[] = {&p};
  (void)hipLaunchCooperativeKernel((const void*)fused_rnn, dim3(256), dim3(256),
                                   args, 155648, stream);
}

// Round 12
// 584.594 us; speedup vs baseline: 1.5447x; 1.1274x over previous
//
#include <hip/hip_runtime.h>
#include <hip/hip_cooperative_groups.h>

namespace cg = cooperative_groups;

typedef unsigned short ushort_t;
typedef __attribute__((ext_vector_type(8))) short short8;
typedef __attribute__((ext_vector_type(4))) float floatx4;
typedef __attribute__((ext_vector_type(4))) ushort_t us4;

#define BAR() __builtin_amdgcn_s_barrier()
#define WAITVM(n) \
  __builtin_amdgcn_s_waitcnt(0x0F70 | ((n) & 15) | (((n) >> 4) << 14))
#define CBARRIER() __asm__ __volatile__("" ::: "memory")

template <int N>
__device__ __forceinline__ void waitvm() {
  __builtin_amdgcn_s_waitcnt(0x0F70 | (N & 15) | ((N >> 4) << 14));
}

template <int V> struct Int { static constexpr int value = V; };
template <int C, int N, typename F> struct StaticFor {
  __device__ __forceinline__ static void run(F& f) {
    f(Int<C>{});
    StaticFor<C + 1, N, F>::run(f);
  }
};
template <int N, typename F> struct StaticFor<N, N, F> {
  __device__ __forceinline__ static void run(F&) {}
};
template <int N, typename F>
__device__ __forceinline__ void static_for(F&& f) {
  StaticFor<0, N, F>::run(f);
}

// private h ring: 4 slots, prefetch distance 3, 2 loads/chunk
constexpr int nwp(int c) { int r = 31 - c; if (r > 3) r = 3; return 2 * r; }
// flag path paired ring depth 2 (round-8)
constexpr int nwb(int c) { return (c == 31) ? 0 : 2; }

__device__ __forceinline__ ushort_t f2bf(float f) {
  union { float f; unsigned u; } v; v.f = f;
  unsigned r = v.u + 0x7fffu + ((v.u >> 16) & 1u);
  return (ushort_t)(r >> 16);
}
__device__ __forceinline__ float fast_sigmoid(float x) {
  return 1.f / (1.f + __expf(-x));
}
__device__ __forceinline__ float fast_tanh(float x) {
  return 1.f - 2.f / (__expf(2.f * x) + 1.f);
}

template <int AUX>
__device__ __forceinline__ void gld16x(const void* g, void* l) {
  __builtin_amdgcn_global_load_lds(
      (__attribute__((address_space(1))) void*)g,
      (__attribute__((address_space(3))) void*)l, 16, 0, AUX);
}

// wave-private stage: 32 rows x 32 k (2KB) into slot; offset baked into the
// GLOBAL pointers (offset arg stays 0).
template <int AUX>
__device__ __forceinline__ void stage_priv(const ushort_t* b0,
                                           const ushort_t* b1, short* slot) {
  gld16x<AUX>(b0, slot);
  gld16x<AUX>(b1, slot + 512);
}

// ---- FF staging: 64x64 chunk, 8KB, XOR-8 swizzle ----
__device__ __forceinline__ void stage64(const ushort_t* src, int ldk,
                                        short* dst, int w, int l) {
  int r0 = (w << 3) + (l >> 3);
  int cb0 = (l & 7) ^ (r0 & 7);
  int r1 = 32 + r0;
  int cb1 = (l & 7) ^ (r1 & 7);
  gld16x<0>(src + (size_t)r0 * ldk + (cb0 << 3), dst + (w << 9));
  gld16x<0>(src + (size_t)r1 * ldk + (cb1 << 3), dst + 2048 + (w << 9));
}

// RNN 64-row chunk staging (flag path): 64 rows x 32 k (4KB), block-coop.
template <int AUX>
__device__ __forceinline__ void stage_chunk(const ushort_t* src, short* slot,
                                            int w, int l) {
  int pu = (w << 6) + l;
  int r = pu >> 2;
  int sg = (pu & 3) ^ ((r >> 1) & 3);
  gld16x<AUX>(src + ((size_t)r << 10) + (sg << 3), slot + (w << 9));
}

__device__ __forceinline__ void compute_chunk64(const short* As, const short* Bs,
                                                floatx4 acc[2][2], int wm,
                                                int wn, int lhi, int llo) {
#pragma unroll
  for (int ks = 0; ks < 2; ++ks) {
    short8 a[2], b[2];
#pragma unroll
    for (int tm = 0; tm < 2; ++tm) {
      int m = (wm << 5) + (tm << 4) + llo;
      int ph = ((ks << 2) + lhi) ^ (m & 7);
      a[tm] = *(const short8*)(As + m * 64 + (ph << 3));
    }
#pragma unroll
    for (int tn = 0; tn < 2; ++tn) {
      int n = (wn << 5) + (tn << 4) + llo;
      int ph = ((ks << 2) + lhi) ^ (n & 7);
      b[tn] = *(const short8*)(Bs + n * 64 + (ph << 3));
    }
#pragma unroll
    for (int tm = 0; tm < 2; ++tm)
#pragma unroll
      for (int tn = 0; tn < 2; ++tn)
        acc[tm][tn] = __builtin_amdgcn_mfma_f32_16x16x32_bf16(
            a[tm], b[tn], acc[tm][tn], 0, 0, 0);
  }
}

__device__ __forceinline__ void ff_epilogue(floatx4 acc[2][2], const float* bias,
                                            ushort_t* outb, float* outf, int act,
                                            int m0, int n0, int wm, int wn,
                                            int lhi, int llo) {
#pragma unroll
  for (int tm = 0; tm < 2; ++tm)
#pragma unroll
    for (int tn = 0; tn < 2; ++tn)
#pragma unroll
      for (int i = 0; i < 4; ++i) {
        int gm = m0 + (wm << 5) + (tm << 4) + (lhi << 2) + i;
        int gn = n0 + (wn << 5) + (tn << 4) + llo;
        float v = acc[tm][tn][i];
        if (bias) v += bias[gn];
        if (act == 0) v = fmaxf(v, 0.f);
        if (outb) outb[((size_t)gm << 10) + gn] = f2bf(v);
        if (outf) outf[((size_t)gm << 10) + gn] = v;
      }
}

__device__ void gemm_stream4(const ushort_t* A, const ushort_t* W, int K,
                             const float* bias, ushort_t* outb, float* outf,
                             int act, char* lds, int w, int l, int wm, int wn,
                             int lhi, int llo, int m0, int n0) {
  short* Ab[4] = {(short*)lds, (short*)(lds + 8192), (short*)(lds + 16384),
                  (short*)(lds + 24576)};
  short* Bb[4] = {(short*)(lds + 32768), (short*)(lds + 40960),
                  (short*)(lds + 49152), (short*)(lds + 57344)};
  floatx4 acc[2][2];
#pragma unroll
  for (int i = 0; i < 2; ++i)
#pragma unroll
    for (int j = 0; j < 2; ++j) acc[i][j] = (floatx4){0.f, 0.f, 0.f, 0.f};
  const ushort_t* Abase = A + (size_t)m0 * K;
  const ushort_t* Bbase = W + (size_t)n0 * K;
  int nc = K >> 6;
#pragma unroll
  for (int c0 = 0; c0 < 3; ++c0) {
    stage64(Abase + (c0 << 6), K, Ab[c0], w, l);
    stage64(Bbase + (c0 << 6), K, Bb[c0], w, l);
  }
  for (int c = 0; c < nc; ++c) {
    int nxt = c + 3;
    if (nxt < nc) {
      stage64(Abase + (nxt << 6), K, Ab[nxt & 3], w, l);
      stage64(Bbase + (nxt << 6), K, Bb[nxt & 3], w, l);
      WAITVM(12);
    } else if (nc - c == 3) {
      WAITVM(8);
    } else if (nc - c == 2) {
      WAITVM(4);
    } else {
      WAITVM(0);
    }
    BAR();
    CBARRIER();
    compute_chunk64(Ab[c & 3], Bb[c & 3], acc, wm, wn, lhi, llo);
    BAR();
  }
  ff_epilogue(acc, bias, outb, outf, act, m0, n0, wm, wn, lhi, llo);
}

// Global two-level barrier with full fences.
__device__ __forceinline__ void gbar(unsigned* area, unsigned seq, int t, int bid) {
  __syncthreads();
  if (t == 0) {
    __threadfence();
    unsigned old = atomicAdd(&area[(bid & 15) << 4], 1u);
    if (old == (seq << 4) - 1u) atomicAdd(&area[256], 1u);
    while (__hip_atomic_load(&area[256], __ATOMIC_RELAXED,
                             __HIP_MEMORY_SCOPE_AGENT) < (seq << 4))
      __builtin_amdgcn_s_sleep(1);
    __threadfence();
  }
  __syncthreads();
}

struct KP {
  const float *x, *W1, *b1, *W2, *b2, *Wih, *Whh, *bih, *bhh, *Wa, *ba;
  ushort_t *Xb, *W1b, *W2b, *Wihb, *Whhb, *Wsmb, *X1b, *Xlb, *Hb0, *Hb1;
  float *xw, *bias, *pacc, *probs, *hxout;
  unsigned* barrier;
};

__global__ __launch_bounds__(256, 1) void fused_rnn(KP p) {
  extern __shared__ char lds[];
  cg::grid_group grid = cg::this_grid();
  const int t = threadIdx.x;
  const int w = t >> 6, l = t & 63;
  const int wm = w >> 1, wn = w & 1;
  const int lhi = l >> 4, llo = l & 15;
  const int bid = blockIdx.x;
  const int m0f = (bid >> 4) << 6, n0f = (bid & 15) << 6;
  // RNN mapping: m-group = bid&15 -> all 16 peers share bid%8 (one XCD under
  // round-robin dispatch). Verified at runtime; falls back to sc1 if not.
  const int mgrp = bid & 15, nblk = bid >> 4;
  const int m0r = mgrp << 6, n0r = nblk << 6;
  const int gid = bid * 256 + t;

  // ---- phase 0 ----
  {
    const float4* xf = (const float4*)p.x;
    const float4* w1f = (const float4*)p.W1;
    const float4* w2f = (const float4*)p.W2;
    const float4* wif = (const float4*)p.Wih;
    const float4* whf = (const float4*)p.Whh;
    for (int i = gid; i < 1048576; i += 65536) {
      float4 v = xf[i];
      us4 o;
      o.x = f2bf(v.x); o.y = f2bf(v.y); o.z = f2bf(v.z); o.w = f2bf(v.w);
      ((us4*)p.Xb)[i] = o;
      float4 u = w1f[i];
      o.x = f2bf(u.x); o.y = f2bf(u.y); o.z = f2bf(u.z); o.w = f2bf(u.w);
      ((us4*)p.W1b)[i] = o;
      if (i < 262144) {
        float4 a = w2f[i];
        o.x = f2bf(a.x); o.y = f2bf(a.y); o.z = f2bf(a.z); o.w = f2bf(a.w);
        ((us4*)p.W2b)[i] = o;
        float4 pp = wif[i];
        o.x = f2bf(pp.x); o.y = f2bf(pp.y); o.z = f2bf(pp.z); o.w = f2bf(pp.w);
        ((us4*)p.Wihb)[i] = o;
        float4 q = whf[i];
        o.x = f2bf(q.x); o.y = f2bf(q.y); o.z = f2bf(q.z); o.w = f2bf(q.w);
        ((us4*)p.Whhb)[i] = o;
        o.x = f2bf(pp.x + q.x); o.y = f2bf(pp.y + q.y);
        o.z = f2bf(pp.z + q.z); o.w = f2bf(pp.w + q.w);
        ((us4*)p.Wsmb)[i] = o;
      }
    }
    p.pacc[gid] = 0.f;
    if (gid < 1024) p.bias[gid] = p.bih[gid] + p.bhh[gid];
    if (gid < 4608) p.barrier[gid] = 0u;
  }
  grid.sync();

  // ---- FF phases ----
  gemm_stream4(p.Xb, p.W1b, 4096, p.b1, p.X1b, nullptr, 0, lds, w, l, wm, wn,
               lhi, llo, m0f, n0f);
  gbar(p.barrier, 1, t, bid);
  gemm_stream4(p.X1b, p.W2b, 1024, p.b2, p.Xlb, nullptr, 0, lds, w, l, wm, wn,
               lhi, llo, m0f, n0f);
  gbar(p.barrier, 2, t, bid);
  gemm_stream4(p.Xlb, p.Wihb, 1024, nullptr, nullptr, p.xw, 2, lds, w, l, wm,
               wn, lhi, llo, m0f, n0f);
  gbar(p.barrier, 3, t, bid);

  // ---- publish XCD id ----
  unsigned xccid;
  __asm__ __volatile__("s_getreg_b32 %0, hwreg(HW_REG_XCC_ID)" : "=s"(xccid));
  if (t == 0)
    __hip_atomic_store(&p.barrier[1024 + (mgrp << 4) + nblk],
                       1000u + (xccid & 15u), __ATOMIC_RELAXED,
                       __HIP_MEMORY_SCOPE_AGENT);

  // ---- resident FULL Wsum slab (rows n0r..n0r+63, K=1024, 128 KB) ----
  short* slab = (short*)lds;
  {
    const ushort_t* Wn = p.Wsmb + ((size_t)n0r << 10);
#pragma unroll
    for (int i = 0; i < 32; ++i) {
      int c = t + (i << 8);
      int r = c >> 7, cc = c & 127;
      int pc = (cc & ~7) | ((cc & 7) ^ (r & 7));
      short8 v = *(const short8*)(Wn + ((size_t)r << 10) + (cc << 3));
      *(short8*)(slab + (r << 10) + (pc << 3)) = v;
    }
  }
  gbar(p.barrier, 4, t, bid);

  // ---- m-group locality check ----
  unsigned myx = 0u;
  if (l < 16)
    myx = __hip_atomic_load(&p.barrier[1024 + (mgrp << 4) + l],
                            __ATOMIC_RELAXED, __HIP_MEMORY_SCOPE_AGENT);
  unsigned x0 = __shfl(myx, 0);
  const bool local = __all((l >= 16) || (myx == x0));

  // LDS after slab: 32KB region.
  //  non-flag: wave-private h rings, wave w at +w*8KB, 4 slots x 2KB
  //  flag:     block-coop 6 x 4KB ring (separated by step-end syncthreads)
  short* priv = (short*)(lds + 131072) + w * 4096;
  short* ring = (short*)(lds + 131072);
  ushort_t* Hb[2] = {p.Hb0, p.Hb1};
  unsigned* mbar = p.barrier + 320 + (mgrp << 4);

  int gnb[2], gmv[2];
#pragma unroll
  for (int tn = 0; tn < 2; ++tn)
    gnb[tn] = n0r + (wn << 5) + (tn << 4) + (lhi << 2);
#pragma unroll
  for (int tm = 0; tm < 2; ++tm)
    gmv[tm] = m0r + (wm << 5) + (tm << 4) + llo;
  float bias_r[2][4], wa_r[2][4], xw_r[2][2][4];
#pragma unroll
  for (int tn = 0; tn < 2; ++tn)
#pragma unroll
    for (int i = 0; i < 4; ++i) {
      bias_r[tn][i] = p.bias[gnb[tn] + i];
      wa_r[tn][i] = p.Wa[gnb[tn] + i];
    }
#pragma unroll
  for (int tm = 0; tm < 2; ++tm)
#pragma unroll
    for (int tn = 0; tn < 2; ++tn)
#pragma unroll
      for (int i = 0; i < 4; ++i)
        xw_r[tm][tn][i] = p.xw[((size_t)gmv[tm] << 10) + gnb[tn] + i];

  const float ba0 = p.ba[0];
  // private-stage per-lane source offsets (within this wave's 32 h rows)
  const int prow = (wm << 5) + (l >> 2);           // j=0 rows
  const int pseg = (l & 3) ^ ((l >> 3) & 3);
  const int poff0 = (prow << 10) + (pseg << 3);    // shorts
  const int poff1 = poff0 + (16 << 10);            // +16 rows
  // private-slot read offsets (B-fragment), step-invariant
  int offb[2];
#pragma unroll
  for (int tm = 0; tm < 2; ++tm) {
    int rl = (tm << 4) + llo;
    offb[tm] = rl * 32 + ((lhi ^ ((rl >> 1) & 3)) << 3);
  }
  short* ps[4] = {priv, priv + 1024, priv + 2048, priv + 3072};

  auto runsteps = [&](auto LC) {
    constexpr bool LOCAL = (decltype(LC)::value != 0);
    constexpr int AUXH = LOCAL ? 1 : 17;  // sc0 (L2-local) vs sc0|sc1 (MALL)
    for (int st = 0; st < 64; ++st) {
      const ushort_t* hbase =
          ((st == 0) ? p.Xlb : Hb[st & 1]) + ((size_t)m0r << 10);
      bool flag = st && !(st & 15);
      floatx4 acc[2][2];  // [tn][tm]
#pragma unroll
      for (int i = 0; i < 2; ++i)
#pragma unroll
        for (int j = 0; j < 2; ++j) acc[i][j] = (floatx4){0.f, 0.f, 0.f, 0.f};

      if (!flag) {
        // wave-private h staging: zero intra-loop barriers, depth 4/dist 3
        const ushort_t* hp0 = hbase + poff0;
        const ushort_t* hp1 = hbase + poff1;
        stage_priv<AUXH>(hp0, hp1, ps[0]);
        stage_priv<AUXH>(hp0 + 32, hp1 + 32, ps[1]);
        stage_priv<AUXH>(hp0 + 64, hp1 + 64, ps[2]);
        static_for<32>([&](auto ic) {
          constexpr int c = decltype(ic)::value;
          if constexpr (c + 3 < 32)
            stage_priv<AUXH>(hp0 + ((c + 3) << 5), hp1 + ((c + 3) << 5),
                             ps[(c + 3) & 3]);
          waitvm<nwp(c)>();
          CBARRIER();
          const short* hs = ps[c & 3];
          short8 afr[2], bfr[2];
#pragma unroll
          for (int tn = 0; tn < 2; ++tn) {
            int na = (wn << 5) + (tn << 4) + llo;
            int u = (c << 2) + lhi;
            int pu = (u & ~7) | ((u & 7) ^ (na & 7));
            afr[tn] = *(const short8*)(slab + (na << 10) + (pu << 3));
          }
#pragma unroll
          for (int tm = 0; tm < 2; ++tm)
            bfr[tm] = *(const short8*)(hs + offb[tm]);
#pragma unroll
          for (int tn = 0; tn < 2; ++tn)
#pragma unroll
            for (int tm = 0; tm < 2; ++tm)
              acc[tn][tm] = __builtin_amdgcn_mfma_f32_16x16x32_bf16(
                  afr[tn], bfr[tm], acc[tn][tm], 0, 0, 0);
        });
      } else {
        // block-coop W+h staging (round-8 proven), 3 steps only
        const ushort_t* wbase = p.Whhb + ((size_t)n0r << 10);
#pragma unroll
        for (int j = 0; j < 2; ++j) {
          stage_chunk<0>(wbase + (j << 5), ring + j * 2048, w, l);
          stage_chunk<AUXH>(hbase + (j << 5), ring + (3 + j) * 2048, w, l);
        }
        static_for<32>([&](auto icc) {
          constexpr int c = decltype(icc)::value;
          waitvm<nwb(c)>();
          BAR();
          CBARRIER();
          if (c + 2 < 32) {
            stage_chunk<0>(wbase + ((c + 2) << 5), ring + ((c + 2) % 3) * 2048,
                           w, l);
            stage_chunk<AUXH>(hbase + ((c + 2) << 5),
                              ring + (3 + (c + 2) % 3) * 2048, w, l);
          }
          const short* wslot = ring + (c % 3) * 2048;
          const short* hslot = ring + (3 + c % 3) * 2048;
          short8 afr[2], bfr[2];
#pragma unroll
          for (int tn = 0; tn < 2; ++tn) {
            int na = (wn << 5) + (tn << 4) + llo;
            afr[tn] = *(const short8*)(wslot + na * 32 +
                                       ((lhi ^ ((na >> 1) & 3)) << 3));
          }
#pragma unroll
          for (int tm = 0; tm < 2; ++tm) {
            int mb = (wm << 5) + (tm << 4) + llo;
            bfr[tm] = *(const short8*)(hslot + mb * 32 +
                                       ((lhi ^ ((mb >> 1) & 3)) << 3));
          }
#pragma unroll
          for (int tn = 0; tn < 2; ++tn)
#pragma unroll
            for (int tm = 0; tm < 2; ++tm)
              acc[tn][tm] = __builtin_amdgcn_mfma_f32_16x16x32_bf16(
                  afr[tn], bfr[tm], acc[tn][tm], 0, 0, 0);
        });
      }

      // ---- epilogue ----
      bool last = (st == 63);
      ushort_t* Hnext = Hb[(st + 1) & 1];
      float hv[2][2][4];  // [tn][tm][i]
#pragma unroll
      for (int tn = 0; tn < 2; ++tn)
#pragma unroll
        for (int tm = 0; tm < 2; ++tm)
#pragma unroll
          for (int i = 0; i < 4; ++i) {
            float v = acc[tn][tm][i] + bias_r[tn][i];
            if (flag) v += xw_r[tm][tn][i];
            hv[tn][tm][i] = fast_tanh(v);
          }
      if (!last) {
#pragma unroll
        for (int tn = 0; tn < 2; ++tn)
#pragma unroll
          for (int tm = 0; tm < 2; ++tm) {
            unsigned long long pk =
                (unsigned long long)f2bf(hv[tn][tm][0]) |
                ((unsigned long long)f2bf(hv[tn][tm][1]) << 16) |
                ((unsigned long long)f2bf(hv[tn][tm][2]) << 32) |
                ((unsigned long long)f2bf(hv[tn][tm][3]) << 48);
            ushort_t* dst = Hnext + ((size_t)gmv[tm] << 10) + gnb[tn];
            if (LOCAL) {
              __asm__ __volatile__("global_store_dwordx2 %0, %1, off"
                                   :
                                   : "v"(dst), "v"(pk)
                                   : "memory");
            } else {
              __asm__ __volatile__("global_store_dwordx2 %0, %1, off sc0 sc1"
                                   :
                                   : "v"(dst), "v"(pk)
                                   : "memory");
            }
          }
      } else {
#pragma unroll
        for (int tn = 0; tn < 2; ++tn)
#pragma unroll
          for (int tm = 0; tm < 2; ++tm) {
            float4 o = make_float4(hv[tn][tm][0], hv[tn][tm][1], hv[tn][tm][2],
                                   hv[tn][tm][3]);
            *(float4*)(p.hxout + ((size_t)gmv[tm] << 10) + gnb[tn]) = o;
          }
      }
      // actor partials issued AFTER h stores: 2 atomics/wave may stay in
      // flight past the barrier (waitvm<2>) — off the critical path.
#pragma unroll
      for (int tm = 0; tm < 2; ++tm) {
        float s = 0.f;
#pragma unroll
        for (int tn = 0; tn < 2; ++tn)
#pragma unroll
          for (int i = 0; i < 4; ++i) s += hv[tn][tm][i] * wa_r[tn][i];
        s += __shfl_xor(s, 16);
        s += __shfl_xor(s, 32);
        if (l < 16) atomicAdd(&p.pacc[(st << 10) + gmv[tm]], s);
      }

      // ---- m-group barrier ----
      if (!last) {
        waitvm<2>();  // h stores drained; pacc atomics may remain in flight
        __syncthreads();
        if (t == 0) {
          atomicAdd(mbar, 1u);
          unsigned tgt = (unsigned)(st + 1) << 4;
          while (__hip_atomic_load(mbar, __ATOMIC_RELAXED,
                                   __HIP_MEMORY_SCOPE_AGENT) < tgt)
            __builtin_amdgcn_s_sleep(1);
        }
        __syncthreads();
      } else {
        WAITVM(0);
      }
    }
  };
  if (local) runsteps(Int<1>{});
  else runsteps(Int<0>{});

  gbar(p.barrier, 5, t, bid);
  p.probs[gid] = fast_sigmoid(p.pacc[gid] + ba0);
}

extern "C" void kernel_launch(void* const* d_in, const int* in_sizes, int n_in,
                              void* d_out, int out_size, void* d_ws,
                              size_t ws_size, hipStream_t stream) {
  char* ws = (char*)d_ws;
  KP p;
  p.x = (const float*)d_in[0];
  p.W1 = (const float*)d_in[1];
  p.b1 = (const float*)d_in[2];
  p.W2 = (const float*)d_in[3];
  p.b2 = (const float*)d_in[4];
  p.Wih = (const float*)d_in[5];
  p.Whh = (const float*)d_in[6];
  p.bih = (const float*)d_in[7];
  p.bhh = (const float*)d_in[8];
  p.Wa = (const float*)d_in[9];
  p.ba = (const float*)d_in[10];
  p.Xb = (ushort_t*)(ws);
  p.W1b = (ushort_t*)(ws + ((size_t)8 << 20));
  p.W2b = (ushort_t*)(ws + ((size_t)16 << 20));
  p.Wihb = (ushort_t*)(ws + ((size_t)18 << 20));
  p.Whhb = (ushort_t*)(ws + ((size_t)20 << 20));
  p.Wsmb = (ushort_t*)(ws + ((size_t)22 << 20));
  p.X1b = (ushort_t*)(ws + ((size_t)24 << 20));
  p.Xlb = (ushort_t*)(ws + ((size_t)26 << 20));
  p.Hb0 = (ushort_t*)(ws + ((size_t)28 << 20));
  p.Hb1 = (ushort_t*)(ws + ((size_t)30 << 20));
  p.xw = (float*)(ws + ((size_t)32 << 20));
  p.bias = (float*)(ws + ((size_t)36 << 20));
  p.pacc = (float*)(ws + ((size_t)36 << 20) + 4096);
  p.barrier = (unsigned*)(ws + ((size_t)36 << 20) + 4096 + 262144);
  p.probs = (float*)d_out;
  p.hxout = (float*)d_out + 65536;

  (void)hipFuncSetAttribute((const void*)fused_rnn,
                            hipFuncAttributeMaxDynamicSharedMemorySize, 163840);
  void* args[] = {&p};
  (void)hipLaunchCooperativeKernel((const void*)fused_rnn, dim3(256), dim3(256),
                                   args, 163840, stream);
}

// Round 14
// 554.571 us; speedup vs baseline: 1.6284x; 1.0541x over previous
//
#include <hip/hip_runtime.h>
#include <hip/hip_cooperative_groups.h>

namespace cg = cooperative_groups;

typedef unsigned short ushort_t;
typedef __attribute__((ext_vector_type(8))) short short8;
typedef __attribute__((ext_vector_type(4))) float floatx4;
typedef __attribute__((ext_vector_type(4))) ushort_t us4;

#define BAR() __builtin_amdgcn_s_barrier()
#define WAITVM(n) \
  __builtin_amdgcn_s_waitcnt(0x0F70 | ((n) & 15) | (((n) >> 4) << 14))
#define CBARRIER() __asm__ __volatile__("" ::: "memory")

template <int N>
__device__ __forceinline__ void waitvm() {
  __builtin_amdgcn_s_waitcnt(0x0F70 | (N & 15) | ((N >> 4) << 14));
}

template <int V> struct Int { static constexpr int value = V; };
template <int C, int N, typename F> struct StaticFor {
  __device__ __forceinline__ static void run(F& f) {
    f(Int<C>{});
    StaticFor<C + 1, N, F>::run(f);
  }
};
template <int N, typename F> struct StaticFor<N, N, F> {
  __device__ __forceinline__ static void run(F&) {}
};
template <int N, typename F>
__device__ __forceinline__ void static_for(F&& f) {
  StaticFor<0, N, F>::run(f);
}

// private h ring: 4 slots, prefetch distance 3, 2 loads/chunk
constexpr int nwp(int c) { int r = 31 - c; if (r > 3) r = 3; return 2 * r; }
// flag path paired ring depth 2
constexpr int nwb(int c) { return (c == 31) ? 0 : 2; }

__device__ __forceinline__ ushort_t f2bf(float f) {
  union { float f; unsigned u; } v; v.f = f;
  unsigned r = v.u + 0x7fffu + ((v.u >> 16) & 1u);
  return (ushort_t)(r >> 16);
}
__device__ __forceinline__ float fast_sigmoid(float x) {
  return 1.f / (1.f + __expf(-x));
}
__device__ __forceinline__ float fast_tanh(float x) {
  return 1.f - 2.f / (__expf(2.f * x) + 1.f);
}

template <int AUX>
__device__ __forceinline__ void gld16x(const void* g, void* l) {
  __builtin_amdgcn_global_load_lds(
      (__attribute__((address_space(1))) void*)g,
      (__attribute__((address_space(3))) void*)l, 16, 0, AUX);
}

template <int AUX>
__device__ __forceinline__ void stage_priv(const ushort_t* b0,
                                           const ushort_t* b1, short* slot) {
  gld16x<AUX>(b0, slot);
  gld16x<AUX>(b1, slot + 512);
}

// ---- FF staging: 64x64 chunk, 8KB, XOR-8 swizzle ----
__device__ __forceinline__ void stage64(const ushort_t* src, int ldk,
                                        short* dst, int w, int l) {
  int r0 = (w << 3) + (l >> 3);
  int cb0 = (l & 7) ^ (r0 & 7);
  int r1 = 32 + r0;
  int cb1 = (l & 7) ^ (r1 & 7);
  gld16x<0>(src + (size_t)r0 * ldk + (cb0 << 3), dst + (w << 9));
  gld16x<0>(src + (size_t)r1 * ldk + (cb1 << 3), dst + 2048 + (w << 9));
}

// RNN 64-row chunk staging (flag path): 64 rows x 32 k (4KB), block-coop.
template <int AUX>
__device__ __forceinline__ void stage_chunk(const ushort_t* src, short* slot,
                                            int w, int l) {
  int pu = (w << 6) + l;
  int r = pu >> 2;
  int sg = (pu & 3) ^ ((r >> 1) & 3);
  gld16x<AUX>(src + ((size_t)r << 10) + (sg << 3), slot + (w << 9));
}

__device__ __forceinline__ void compute_chunk64(const short* As, const short* Bs,
                                                floatx4 acc[2][2], int wm,
                                                int wn, int lhi, int llo) {
#pragma unroll
  for (int ks = 0; ks < 2; ++ks) {
    short8 a[2], b[2];
#pragma unroll
    for (int tm = 0; tm < 2; ++tm) {
      int m = (wm << 5) + (tm << 4) + llo;
      int ph = ((ks << 2) + lhi) ^ (m & 7);
      a[tm] = *(const short8*)(As + m * 64 + (ph << 3));
    }
#pragma unroll
    for (int tn = 0; tn < 2; ++tn) {
      int n = (wn << 5) + (tn << 4) + llo;
      int ph = ((ks << 2) + lhi) ^ (n & 7);
      b[tn] = *(const short8*)(Bs + n * 64 + (ph << 3));
    }
#pragma unroll
    for (int tm = 0; tm < 2; ++tm)
#pragma unroll
      for (int tn = 0; tn < 2; ++tn)
        acc[tm][tn] = __builtin_amdgcn_mfma_f32_16x16x32_bf16(
            a[tm], b[tn], acc[tm][tn], 0, 0, 0);
  }
}

__device__ __forceinline__ void ff_epilogue(floatx4 acc[2][2], const float* bias,
                                            ushort_t* outb, float* outf, int act,
                                            int m0, int n0, int wm, int wn,
                                            int lhi, int llo) {
#pragma unroll
  for (int tm = 0; tm < 2; ++tm)
#pragma unroll
    for (int tn = 0; tn < 2; ++tn)
#pragma unroll
      for (int i = 0; i < 4; ++i) {
        int gm = m0 + (wm << 5) + (tm << 4) + (lhi << 2) + i;
        int gn = n0 + (wn << 5) + (tn << 4) + llo;
        float v = acc[tm][tn][i];
        if (bias) v += bias[gn];
        if (act == 0) v = fmaxf(v, 0.f);
        if (outb) outb[((size_t)gm << 10) + gn] = f2bf(v);
        if (outf) outf[((size_t)gm << 10) + gn] = v;
      }
}

__device__ void gemm_stream4(const ushort_t* A, const ushort_t* W, int K,
                             const float* bias, ushort_t* outb, float* outf,
                             int act, char* lds, int w, int l, int wm, int wn,
                             int lhi, int llo, int m0, int n0) {
  short* Ab[4] = {(short*)lds, (short*)(lds + 8192), (short*)(lds + 16384),
                  (short*)(lds + 24576)};
  short* Bb[4] = {(short*)(lds + 32768), (short*)(lds + 40960),
                  (short*)(lds + 49152), (short*)(lds + 57344)};
  floatx4 acc[2][2];
#pragma unroll
  for (int i = 0; i < 2; ++i)
#pragma unroll
    for (int j = 0; j < 2; ++j) acc[i][j] = (floatx4){0.f, 0.f, 0.f, 0.f};
  const ushort_t* Abase = A + (size_t)m0 * K;
  const ushort_t* Bbase = W + (size_t)n0 * K;
  int nc = K >> 6;
#pragma unroll
  for (int c0 = 0; c0 < 3; ++c0) {
    stage64(Abase + (c0 << 6), K, Ab[c0], w, l);
    stage64(Bbase + (c0 << 6), K, Bb[c0], w, l);
  }
  for (int c = 0; c < nc; ++c) {
    int nxt = c + 3;
    if (nxt < nc) {
      stage64(Abase + (nxt << 6), K, Ab[nxt & 3], w, l);
      stage64(Bbase + (nxt << 6), K, Bb[nxt & 3], w, l);
      WAITVM(12);
    } else if (nc - c == 3) {
      WAITVM(8);
    } else if (nc - c == 2) {
      WAITVM(4);
    } else {
      WAITVM(0);
    }
    BAR();
    CBARRIER();
    compute_chunk64(Ab[c & 3], Bb[c & 3], acc, wm, wn, lhi, llo);
    BAR();
  }
  ff_epilogue(acc, bias, outb, outf, act, m0, n0, wm, wn, lhi, llo);
}

// Global two-level barrier with full fences.
__device__ __forceinline__ void gbar(unsigned* area, unsigned seq, int t, int bid) {
  __syncthreads();
  if (t == 0) {
    __threadfence();
    unsigned old = atomicAdd(&area[(bid & 15) << 4], 1u);
    if (old == (seq << 4) - 1u) atomicAdd(&area[256], 1u);
    while (__hip_atomic_load(&area[256], __ATOMIC_RELAXED,
                             __HIP_MEMORY_SCOPE_AGENT) < (seq << 4))
      __builtin_amdgcn_s_sleep(1);
    __threadfence();
  }
  __syncthreads();
}

struct KP {
  const float *x, *W1, *b1, *W2, *b2, *Wih, *Whh, *bih, *bhh, *Wa, *ba;
  ushort_t *Xb, *W1b, *W2b, *Wihb, *Whhb, *Wsmb, *X1b, *Xlb, *Hb0, *Hb1;
  float *xw, *bias, *pacc2, *probs, *hxout;
  unsigned* barrier;
};

__global__ __launch_bounds__(256, 1) void fused_rnn(KP p) {
  extern __shared__ char lds[];
  cg::grid_group grid = cg::this_grid();
  const int t = threadIdx.x;
  const int w = t >> 6, l = t & 63;
  const int wm = w >> 1, wn = w & 1;
  const int lhi = l >> 4, llo = l & 15;
  const int bid = blockIdx.x;
  const int m0f = (bid >> 4) << 6, n0f = (bid & 15) << 6;
  // RNN mapping: m-group = bid&15 -> all 16 peers share bid%8 (one XCD under
  // round-robin dispatch). Verified at runtime; falls back to sc1 if not.
  const int mgrp = bid & 15, nblk = bid >> 4;
  const int m0r = mgrp << 6, n0r = nblk << 6;
  const int gid = bid * 256 + t;

  // ---- phase 0 ----
  {
    const float4* xf = (const float4*)p.x;
    const float4* w1f = (const float4*)p.W1;
    const float4* w2f = (const float4*)p.W2;
    const float4* wif = (const float4*)p.Wih;
    const float4* whf = (const float4*)p.Whh;
    for (int i = gid; i < 1048576; i += 65536) {
      float4 v = xf[i];
      us4 o;
      o.x = f2bf(v.x); o.y = f2bf(v.y); o.z = f2bf(v.z); o.w = f2bf(v.w);
      ((us4*)p.Xb)[i] = o;
      float4 u = w1f[i];
      o.x = f2bf(u.x); o.y = f2bf(u.y); o.z = f2bf(u.z); o.w = f2bf(u.w);
      ((us4*)p.W1b)[i] = o;
      if (i < 262144) {
        float4 a = w2f[i];
        o.x = f2bf(a.x); o.y = f2bf(a.y); o.z = f2bf(a.z); o.w = f2bf(a.w);
        ((us4*)p.W2b)[i] = o;
        float4 pp = wif[i];
        o.x = f2bf(pp.x); o.y = f2bf(pp.y); o.z = f2bf(pp.z); o.w = f2bf(pp.w);
        ((us4*)p.Wihb)[i] = o;
        float4 q = whf[i];
        o.x = f2bf(q.x); o.y = f2bf(q.y); o.z = f2bf(q.z); o.w = f2bf(q.w);
        ((us4*)p.Whhb)[i] = o;
        o.x = f2bf(pp.x + q.x); o.y = f2bf(pp.y + q.y);
        o.z = f2bf(pp.z + q.z); o.w = f2bf(pp.w + q.w);
        ((us4*)p.Wsmb)[i] = o;
      }
    }
    if (gid < 1024) p.bias[gid] = p.bih[gid] + p.bhh[gid];
    if (gid < 2048) p.barrier[gid] = 0u;
  }
  grid.sync();

  // ---- publish XCD id immediately (slots read much later -> no wait) ----
  unsigned xccid;
  __asm__ __volatile__("s_getreg_b32 %0, hwreg(HW_REG_XCC_ID)" : "=s"(xccid));
  if (t == 0)
    __hip_atomic_store(&p.barrier[1024 + (mgrp << 4) + nblk],
                       1000u + (xccid & 15u), __ATOMIC_RELAXED,
                       __HIP_MEMORY_SCOPE_AGENT);

  // ---- FF phases ----
  gemm_stream4(p.Xb, p.W1b, 4096, p.b1, p.X1b, nullptr, 0, lds, w, l, wm, wn,
               lhi, llo, m0f, n0f);
  gbar(p.barrier, 1, t, bid);
  gemm_stream4(p.X1b, p.W2b, 1024, p.b2, p.Xlb, nullptr, 0, lds, w, l, wm, wn,
               lhi, llo, m0f, n0f);
  gbar(p.barrier, 2, t, bid);
  gemm_stream4(p.Xlb, p.Wihb, 1024, nullptr, nullptr, p.xw, 2, lds, w, l, wm,
               wn, lhi, llo, m0f, n0f);
  gbar(p.barrier, 3, t, bid);

  // ---- resident FULL Wsum slab (rows n0r..n0r+63, K=1024, 128 KB) ----
  short* slab = (short*)lds;
  {
    const ushort_t* Wn = p.Wsmb + ((size_t)n0r << 10);
#pragma unroll
    for (int i = 0; i < 32; ++i) {
      int c = t + (i << 8);
      int r = c >> 7, cc = c & 127;
      int pc = (cc & ~7) | ((cc & 7) ^ (r & 7));
      short8 v = *(const short8*)(Wn + ((size_t)r << 10) + (cc << 3));
      *(short8*)(slab + (r << 10) + (pc << 3)) = v;
    }
  }
  __syncthreads();

  // ---- m-group locality check (one-shot monotone slots; usually instant) ----
  unsigned myx = 0u;
  if (l < 16) {
    do {
      myx = __hip_atomic_load(&p.barrier[1024 + (mgrp << 4) + l],
                              __ATOMIC_RELAXED, __HIP_MEMORY_SCOPE_AGENT);
    } while (myx < 1000u);
  }
  unsigned x0 = __shfl(myx, 0);
  const bool local = __all((l >= 16) || (myx == x0));

  // LDS after slab: 32KB. non-flag: wave-private rings (w*8KB, 4x2KB slots);
  // flag: block-coop 6x4KB ring (path switches covered by step-end syncthreads)
  short* priv = (short*)(lds + 131072) + w * 4096;
  short* ring = (short*)(lds + 131072);
  ushort_t* Hb[2] = {p.Hb0, p.Hb1};
  unsigned* mbar = p.barrier + 320 + (mgrp << 4);

  int gnb[2], gmv[2];
#pragma unroll
  for (int tn = 0; tn < 2; ++tn)
    gnb[tn] = n0r + (wn << 5) + (tn << 4) + (lhi << 2);
#pragma unroll
  for (int tm = 0; tm < 2; ++tm)
    gmv[tm] = m0r + (wm << 5) + (tm << 4) + llo;
  float bias_r[2][4], wa_r[2][4], xw_r[2][2][4];
#pragma unroll
  for (int tn = 0; tn < 2; ++tn)
#pragma unroll
    for (int i = 0; i < 4; ++i) {
      bias_r[tn][i] = p.bias[gnb[tn] + i];
      wa_r[tn][i] = p.Wa[gnb[tn] + i];
    }
#pragma unroll
  for (int tm = 0; tm < 2; ++tm)
#pragma unroll
    for (int tn = 0; tn < 2; ++tn)
#pragma unroll
      for (int i = 0; i < 4; ++i)
        xw_r[tm][tn][i] = p.xw[((size_t)gmv[tm] << 10) + gnb[tn] + i];

  const float ba0 = p.ba[0];
  // private-stage per-lane source offsets (within this wave's 32 h rows)
  const int prow = (wm << 5) + (l >> 2);
  const int pseg = (l & 3) ^ ((l >> 3) & 3);
  const int poff0 = (prow << 10) + (pseg << 3);
  const int poff1 = poff0 + (16 << 10);
  int offb[2];
#pragma unroll
  for (int tm = 0; tm < 2; ++tm) {
    int rl = (tm << 4) + llo;
    offb[tm] = rl * 32 + ((lhi ^ ((rl >> 1) & 3)) << 3);
  }
  short* ps[4] = {priv, priv + 1024, priv + 2048, priv + 3072};
  // actor partial slice base: [st][nblk*2+wn][m]
  float* pslice = p.pacc2 + ((size_t)((nblk << 1) | wn) << 10);

  auto runsteps = [&](auto LC) {
    constexpr bool LOCAL = (decltype(LC)::value != 0);
    constexpr int AUXH = LOCAL ? 1 : 17;  // sc0 (L2-local) vs sc0|sc1 (MALL)
    for (int st = 0; st < 64; ++st) {
      const ushort_t* hbase =
          ((st == 0) ? p.Xlb : Hb[st & 1]) + ((size_t)m0r << 10);
      bool flag = st && !(st & 15);
      floatx4 acc[2][2];  // [tn][tm]
#pragma unroll
      for (int i = 0; i < 2; ++i)
#pragma unroll
        for (int j = 0; j < 2; ++j) acc[i][j] = (floatx4){0.f, 0.f, 0.f, 0.f};

      if (!flag) {
        // wave-private h staging: zero intra-loop barriers, depth 4/dist 3
        const ushort_t* hp0 = hbase + poff0;
        const ushort_t* hp1 = hbase + poff1;
        stage_priv<AUXH>(hp0, hp1, ps[0]);
        stage_priv<AUXH>(hp0 + 32, hp1 + 32, ps[1]);
        stage_priv<AUXH>(hp0 + 64, hp1 + 64, ps[2]);
        static_for<32>([&](auto ic) {
          constexpr int c = decltype(ic)::value;
          if constexpr (c + 3 < 32)
            stage_priv<AUXH>(hp0 + ((c + 3) << 5), hp1 + ((c + 3) << 5),
                             ps[(c + 3) & 3]);
          waitvm<nwp(c)>();
          CBARRIER();
          const short* hs = ps[c & 3];
          short8 afr[2], bfr[2];
#pragma unroll
          for (int tn = 0; tn < 2; ++tn) {
            int na = (wn << 5) + (tn << 4) + llo;
            int u = (c << 2) + lhi;
            int pu = (u & ~7) | ((u & 7) ^ (na & 7));
            afr[tn] = *(const short8*)(slab + (na << 10) + (pu << 3));
          }
#pragma unroll
          for (int tm = 0; tm < 2; ++tm)
            bfr[tm] = *(const short8*)(hs + offb[tm]);
#pragma unroll
          for (int tn = 0; tn < 2; ++tn)
#pragma unroll
            for (int tm = 0; tm < 2; ++tm)
              acc[tn][tm] = __builtin_amdgcn_mfma_f32_16x16x32_bf16(
                  afr[tn], bfr[tm], acc[tn][tm], 0, 0, 0);
        });
      } else {
        // block-coop W+h staging (round-8 proven), 3 steps only
        const ushort_t* wbase = p.Whhb + ((size_t)n0r << 10);
#pragma unroll
        for (int j = 0; j < 2; ++j) {
          stage_chunk<0>(wbase + (j << 5), ring + j * 2048, w, l);
          stage_chunk<AUXH>(hbase + (j << 5), ring + (3 + j) * 2048, w, l);
        }
        static_for<32>([&](auto icc) {
          constexpr int c = decltype(icc)::value;
          waitvm<nwb(c)>();
          BAR();
          CBARRIER();
          if (c + 2 < 32) {
            stage_chunk<0>(wbase + ((c + 2) << 5), ring + ((c + 2) % 3) * 2048,
                           w, l);
            stage_chunk<AUXH>(hbase + ((c + 2) << 5),
                              ring + (3 + (c + 2) % 3) * 2048, w, l);
          }
          const short* wslot = ring + (c % 3) * 2048;
          const short* hslot = ring + (3 + c % 3) * 2048;
          short8 afr[2], bfr[2];
#pragma unroll
          for (int tn = 0; tn < 2; ++tn) {
            int na = (wn << 5) + (tn << 4) + llo;
            afr[tn] = *(const short8*)(wslot + na * 32 +
                                       ((lhi ^ ((na >> 1) & 3)) << 3));
          }
#pragma unroll
          for (int tm = 0; tm < 2; ++tm) {
            int mb = (wm << 5) + (tm << 4) + llo;
            bfr[tm] = *(const short8*)(hslot + mb * 32 +
                                       ((lhi ^ ((mb >> 1) & 3)) << 3));
          }
#pragma unroll
          for (int tn = 0; tn < 2; ++tn)
#pragma unroll
            for (int tm = 0; tm < 2; ++tm)
              acc[tn][tm] = __builtin_amdgcn_mfma_f32_16x16x32_bf16(
                  afr[tn], bfr[tm], acc[tn][tm], 0, 0, 0);
        });
      }

      // ---- epilogue ----
      bool last = (st == 63);
      ushort_t* Hnext = Hb[(st + 1) & 1];
      float hv[2][2][4];  // [tn][tm][i]
#pragma unroll
      for (int tn = 0; tn < 2; ++tn)
#pragma unroll
        for (int tm = 0; tm < 2; ++tm)
#pragma unroll
          for (int i = 0; i < 4; ++i) {
            float v = acc[tn][tm][i] + bias_r[tn][i];
            if (flag) v += xw_r[tm][tn][i];
            hv[tn][tm][i] = fast_tanh(v);
          }
      if (!last) {
#pragma unroll
        for (int tn = 0; tn < 2; ++tn)
#pragma unroll
          for (int tm = 0; tm < 2; ++tm) {
            unsigned long long pk =
                (unsigned long long)f2bf(hv[tn][tm][0]) |
                ((unsigned long long)f2bf(hv[tn][tm][1]) << 16) |
                ((unsigned long long)f2bf(hv[tn][tm][2]) << 32) |
                ((unsigned long long)f2bf(hv[tn][tm][3]) << 48);
            ushort_t* dst = Hnext + ((size_t)gmv[tm] << 10) + gnb[tn];
            if (LOCAL) {
              __asm__ __volatile__("global_store_dwordx2 %0, %1, off"
                                   :
                                   : "v"(dst), "v"(pk)
                                   : "memory");
            } else {
              __asm__ __volatile__("global_store_dwordx2 %0, %1, off sc0 sc1"
                                   :
                                   : "v"(dst), "v"(pk)
                                   : "memory");
            }
          }
      } else {
#pragma unroll
        for (int tn = 0; tn < 2; ++tn)
#pragma unroll
          for (int tm = 0; tm < 2; ++tm) {
            float4 o = make_float4(hv[tn][tm][0], hv[tn][tm][1], hv[tn][tm][2],
                                   hv[tn][tm][3]);
            *(float4*)(p.hxout + ((size_t)gmv[tm] << 10) + gnb[tn]) = o;
          }
      }
      // actor partials: PLAIN stores to private slice (no atomics); issued
      // after h stores so waitvm<2> leaves only these in flight.
#pragma unroll
      for (int tm = 0; tm < 2; ++tm) {
        float s = 0.f;
#pragma unroll
        for (int tn = 0; tn < 2; ++tn)
#pragma unroll
          for (int i = 0; i < 4; ++i) s += hv[tn][tm][i] * wa_r[tn][i];
        s += __shfl_xor(s, 16);
        s += __shfl_xor(s, 32);
        if (l < 16) pslice[((size_t)st << 15) + gmv[tm]] = s;
      }

      // ---- m-group barrier ----
      if (!last) {
        waitvm<2>();  // 8 h stores drained; 2 partial stores may be in flight
        __syncthreads();
        if (t == 0) {
          atomicAdd(mbar, 1u);
          unsigned tgt = (unsigned)(st + 1) << 4;
          while (__hip_atomic_load(mbar, __ATOMIC_RELAXED,
                                   __HIP_MEMORY_SCOPE_AGENT) < tgt)
            __builtin_amdgcn_s_sleep(1);
        }
        __syncthreads();
      } else {
        WAITVM(0);
      }
    }
  };
  if (local) runsteps(Int<1>{});
  else runsteps(Int<0>{});

  gbar(p.barrier, 4, t, bid);
  // ---- finalize probs: fixed-order sum of 32 partials ----
  {
    float f = ba0;
    const float* base = p.pacc2 + ((size_t)(gid >> 10) << 15) + (gid & 1023);
#pragma unroll
    for (int j = 0; j < 32; ++j) f += base[(size_t)j << 10];
    p.probs[gid] = fast_sigmoid(f);
  }
}

extern "C" void kernel_launch(void* const* d_in, const int* in_sizes, int n_in,
                              void* d_out, int out_size, void* d_ws,
                              size_t ws_size, hipStream_t stream) {
  char* ws = (char*)d_ws;
  KP p;
  p.x = (const float*)d_in[0];
  p.W1 = (const float*)d_in[1];
  p.b1 = (const float*)d_in[2];
  p.W2 = (const float*)d_in[3];
  p.b2 = (const float*)d_in[4];
  p.Wih = (const float*)d_in[5];
  p.Whh = (const float*)d_in[6];
  p.bih = (const float*)d_in[7];
  p.bhh = (const float*)d_in[8];
  p.Wa = (const float*)d_in[9];
  p.ba = (const float*)d_in[10];
  p.Xb = (ushort_t*)(ws);
  p.W1b = (ushort_t*)(ws + ((size_t)8 << 20));
  p.W2b = (ushort_t*)(ws + ((size_t)16 << 20));
  p.Wihb = (ushort_t*)(ws + ((size_t)18 << 20));
  p.Whhb = (ushort_t*)(ws + ((size_t)20 << 20));
  p.Wsmb = (ushort_t*)(ws + ((size_t)22 << 20));
  p.X1b = (ushort_t*)(ws + ((size_t)24 << 20));
  p.Xlb = (ushort_t*)(ws + ((size_t)26 << 20));
  p.Hb0 = (ushort_t*)(ws + ((size_t)28 << 20));
  p.Hb1 = (ushort_t*)(ws + ((size_t)30 << 20));
  p.xw = (float*)(ws + ((size_t)32 << 20));
  p.bias = (float*)(ws + ((size_t)36 << 20));
  // pacc2 [64][32][1024] fp32 (8 MB) aliases Xb (dead after FF phase 1)
  p.pacc2 = (float*)(ws);
  p.barrier = (unsigned*)(ws + ((size_t)36 << 20) + 4096 + 262144);
  p.probs = (float*)d_out;
  p.hxout = (float*)d_out + 65536;

  (void)hipFuncSetAttribute((const void*)fused_rnn,
                            hipFuncAttributeMaxDynamicSharedMemorySize, 163840);
  void* args[] = {&p};
  (void)hipLaunchCooperativeKernel((const void*)fused_rnn, dim3(256), dim3(256),
                                   args, 163840, stream);
}